// Round 4
// baseline (2361.553 us; speedup 1.0000x reference)
//
#include <hip/hip_runtime.h>

#define NN 50000
#define NE 800000
#define CLAMPV 5.0f
#define BNS 0.9999950000374997f
#define EPAD(c) ((c) + ((c) >> 3))
#define EPSTRIDE 289

typedef __attribute__((ext_vector_type(8))) short s16x8;
typedef __attribute__((ext_vector_type(8))) __bf16 bf16x8;
typedef __attribute__((ext_vector_type(4))) float f32x4;

__device__ inline f32x4 mfma16(s16x8 a, s16x8 b, f32x4 c) {
    return __builtin_amdgcn_mfma_f32_16x16x32_bf16(
        __builtin_bit_cast(bf16x8, a), __builtin_bit_cast(bf16x8, b), c, 0, 0, 0);
}

__device__ inline unsigned short bf16r(float f) {
    unsigned u = __builtin_bit_cast(unsigned, f);
    return (unsigned short)((u + 0x7FFFu + ((u >> 16) & 1u)) >> 16);
}

__device__ inline int pk2(float a, float b) {
    return (int)(unsigned)bf16r(a) | ((int)(unsigned)bf16r(b) << 16);
}

__device__ inline float b2f(unsigned short u) {
    return __builtin_bit_cast(float, (unsigned)u << 16);
}

// ---------------- degree / CSR build ----------------

__global__ __launch_bounds__(256) void k_deg(const int* __restrict__ ei, int* __restrict__ deg) {
    int e = blockIdx.x * 256 + threadIdx.x;
    if (e < NE) atomicAdd(&deg[ei[NE + e]], 1);
}

__global__ __launch_bounds__(1024) void k_scan(const int* __restrict__ deg, int* __restrict__ offs) {
    __shared__ int sm[1024];
    __shared__ int carry;
    if (threadIdx.x == 0) { carry = 0; offs[0] = 0; }
    __syncthreads();
    for (int base = 0; base < NN; base += 1024) {
        int i = base + threadIdx.x;
        int v = (i < NN) ? deg[i] : 0;
        sm[threadIdx.x] = v;
        __syncthreads();
        for (int s = 1; s < 1024; s <<= 1) {
            int t = (threadIdx.x >= s) ? sm[threadIdx.x - s] : 0;
            __syncthreads();
            sm[threadIdx.x] += t;
            __syncthreads();
        }
        if (i < NN) offs[i + 1] = carry + sm[threadIdx.x];
        __syncthreads();
        if (threadIdx.x == 0) carry += sm[1023];
        __syncthreads();
    }
}

__global__ __launch_bounds__(256) void k_fill(const int* __restrict__ ei, const int* __restrict__ offs,
                                              int* __restrict__ cursor, int* __restrict__ csr) {
    int e = blockIdx.x * 256 + threadIdx.x;
    if (e < NE) {
        int d = ei[NE + e];
        int pos = offs[d] + atomicAdd(&cursor[d], 1);
        csr[pos] = e;
    }
}

__global__ __launch_bounds__(256) void k_logdeg(const int* __restrict__ deg, float* __restrict__ logdeg) {
    int i = blockIdx.x * 256 + threadIdx.x;
    if (i < NN) logdeg[i] = logf((float)deg[i] + 1.0f);
}

// Pack fp32 weight W[k][col] into MFMA B-fragment order:
// out[((kt*ncol + col)*4 + kg)*8 + j] = bf16(W[(kt*32 + kg*8 + j)*ncol + col])
__global__ __launch_bounds__(256) void k_pack(const float* __restrict__ W, int ncol, short* __restrict__ out) {
    int idx = blockIdx.x * 256 + threadIdx.x;
    if (idx >= 128 * ncol) return;
    int j = idx & 7; int t = idx >> 3; int kg = t & 3; t >>= 2;
    int col = t % ncol; int kt = t / ncol;
    int k = kt * 32 + kg * 8 + j;
    float v = W[k * ncol + col];
    out[idx] = (short)bf16r(v);
}

// ---------------- per-layer kernels ----------------

// Q/K/V: 8 nodes/block, 256 threads, bf16 packed outputs.
// thread: 2 adjacent cols (c2,c2+1) x 2 rows.
__global__ __launch_bounds__(256) void k_qkv(const float* __restrict__ x,
                                             const float* __restrict__ Wq, const float* __restrict__ bq,
                                             const float* __restrict__ Wk, const float* __restrict__ Wv,
                                             unsigned short* __restrict__ Qh, unsigned short* __restrict__ Kh,
                                             unsigned short* __restrict__ Vh) {
    __shared__ float xs[8][128];
    int n0 = blockIdx.x * 8;
    {
        int row = threadIdx.x >> 5, c4 = (threadIdx.x & 31) * 4;
        *(float4*)&xs[row][c4] = *(const float4*)(x + (size_t)(n0 + row) * 128 + c4);
    }
    __syncthreads();
    int c2 = (threadIdx.x & 63) * 2, rg = threadIdx.x >> 6;
    float2 bqv = *(const float2*)(bq + c2);
    float a[3][2][2];
    a[0][0][0] = bqv.x; a[0][0][1] = bqv.y; a[0][1][0] = bqv.x; a[0][1][1] = bqv.y;
    a[1][0][0] = 0.f; a[1][0][1] = 0.f; a[1][1][0] = 0.f; a[1][1][1] = 0.f;
    a[2][0][0] = 0.f; a[2][0][1] = 0.f; a[2][1][0] = 0.f; a[2][1][1] = 0.f;
    for (int k = 0; k < 128; ++k) {
        float x0 = xs[rg * 2][k], x1 = xs[rg * 2 + 1][k];
        float2 wq = *(const float2*)(Wq + k * 128 + c2);
        float2 wk = *(const float2*)(Wk + k * 128 + c2);
        float2 wv = *(const float2*)(Wv + k * 128 + c2);
        a[0][0][0] += x0 * wq.x; a[0][0][1] += x0 * wq.y; a[0][1][0] += x1 * wq.x; a[0][1][1] += x1 * wq.y;
        a[1][0][0] += x0 * wk.x; a[1][0][1] += x0 * wk.y; a[1][1][0] += x1 * wk.x; a[1][1][1] += x1 * wk.y;
        a[2][0][0] += x0 * wv.x; a[2][0][1] += x0 * wv.y; a[2][1][0] += x1 * wv.x; a[2][1][1] += x1 * wv.y;
    }
#pragma unroll
    for (int rr = 0; rr < 2; ++rr) {
        size_t n = (size_t)(n0 + rg * 2 + rr);
        int cw = c2 >> 1;
        ((int*)Qh)[n * 64 + cw] = pk2(a[0][rr][0], a[0][rr][1]);
        ((int*)Kh)[n * 64 + cw] = pk2(a[1][rr][0], a[1][rr][1]);
        ((int*)Vh)[n * 64 + cw] = pk2(a[2][rr][0], a[2][rr][1]);
    }
}

// Fused edge kernel: Ep GEMM -> elementwise (e_t, sc) -> e_out GEMM with residual.
// 16 edges/block, 4 waves.
__global__ __launch_bounds__(256) void k_edgeA(const float* __restrict__ ea, const int* __restrict__ ei,
                                               const short* __restrict__ Wep, const float* __restrict__ be,
                                               const float* __restrict__ Aw,
                                               const unsigned short* __restrict__ Qh,
                                               const unsigned short* __restrict__ Kh,
                                               unsigned short* __restrict__ e_t, float* __restrict__ sc,
                                               const short* __restrict__ Woep, const float* __restrict__ boe,
                                               float* __restrict__ eout) {
    __shared__ short eas[16 * 128];          // bf16 ea tile, XOR-swizzled
    __shared__ float eaf[16 * 129];          // f32 ea tile (residual)
    __shared__ float ep[16 * EPSTRIDE];      // Ep, EPAD column remap (bank-conflict-free)
    __shared__ short ets[16 * 128];          // bf16 e_t tile, XOR-swizzled
    int e0 = blockIdx.x * 16;
    int t = threadIdx.x;
    int r = t >> 4, ci = t & 15;
    {   // phase 1: stage ea -> bf16 swizzled + f32 copy
        const float4* src = (const float4*)(ea + (size_t)(e0 + r) * 128 + ci * 8);
        float4 v0 = src[0], v1 = src[1];
        int4 pkv;
        pkv.x = pk2(v0.x, v0.y); pkv.y = pk2(v0.z, v0.w);
        pkv.z = pk2(v1.x, v1.y); pkv.w = pk2(v1.z, v1.w);
        int byte = (r * 256 + ci * 16) ^ ((r & 7) << 4);
        *(int4*)((char*)eas + byte) = pkv;
        float* dst = eaf + r * 129 + ci * 8;
        dst[0] = v0.x; dst[1] = v0.y; dst[2] = v0.z; dst[3] = v0.w;
        dst[4] = v1.x; dst[5] = v1.y; dst[6] = v1.z; dst[7] = v1.w;
    }
    __syncthreads();
    int lane = t & 63, w = t >> 6;
    int l15 = lane & 15, kg = lane >> 4;
    {   // phase 2: Ep = eas @ We + be  (16x256)
        f32x4 acc[4];
#pragma unroll
        for (int q = 0; q < 4; ++q) { acc[q][0] = 0.f; acc[q][1] = 0.f; acc[q][2] = 0.f; acc[q][3] = 0.f; }
#pragma unroll
        for (int kt = 0; kt < 4; ++kt) {
            int abyte = (l15 * 256 + kt * 64 + kg * 16) ^ ((l15 & 7) << 4);
            s16x8 a = *(const s16x8*)((const char*)eas + abyte);
#pragma unroll
            for (int q = 0; q < 4; ++q) {
                int col = (w * 4 + q) * 16 + l15;
                s16x8 b = *(const s16x8*)(Wep + ((size_t)((kt * 256 + col) * 4 + kg)) * 8);
                acc[q] = mfma16(a, b, acc[q]);
            }
        }
#pragma unroll
        for (int q = 0; q < 4; ++q) {
            int col = (w * 4 + q) * 16 + l15;
            float bb = be[col];
#pragma unroll
            for (int i = 0; i < 4; ++i)
                ep[(kg * 4 + i) * EPSTRIDE + EPAD(col)] = acc[q][i] + bb;
        }
    }
    __syncthreads();
    {   // phase 3: elementwise — thread t: edge r, head hh, d-slice dbase..dbase+7
        int e = e0 + r;
        int si = ei[e], di = ei[NE + e];
        union { int4 v; unsigned short us[8]; } ku, qu;
        ku.v = *(const int4*)(Kh + (size_t)si * 128 + ci * 8);
        qu.v = *(const int4*)(Qh + (size_t)di * 128 + ci * 8);
        int hh = ci >> 1, dbase = (ci & 1) * 8;
        const float* eprow = ep + r * EPSTRIDE + hh * 36 + 9 * (ci & 1);
        float p = 0.f;
        float etv[8];
#pragma unroll
        for (int j = 0; j < 8; ++j) {
            float kq = b2f(ku.us[j]) + b2f(qu.us[j]);
            float ew = eprow[j];
            float ebv = eprow[18 + j];
            float sv = kq * ew;
            float ss = (sv > 0.f) ? sqrtf(sv) : ((sv < 0.f) ? -sqrtf(-sv) : 0.f);
            float et = fmaxf(ss + ebv, 0.f);
            etv[j] = et;
            p += et * Aw[(dbase + j) * 8 + hh];
        }
        int4 pkv;
        pkv.x = pk2(etv[0], etv[1]); pkv.y = pk2(etv[2], etv[3]);
        pkv.z = pk2(etv[4], etv[5]); pkv.w = pk2(etv[6], etv[7]);
        *(int4*)(e_t + (size_t)e * 128 + ci * 8) = pkv;
        int byte = (r * 256 + ci * 16) ^ ((r & 7) << 4);
        *(int4*)((char*)ets + byte) = pkv;
        p += __shfl_xor(p, 1);
        if ((ci & 1) == 0) {
            float s = fminf(fmaxf(p, -CLAMPV), CLAMPV);
            sc[(size_t)e * 8 + hh] = s;
        }
    }
    __syncthreads();
    {   // phase 4: e_out = (ea + ets @ Woe + boe) * BNS  (16x128)
        f32x4 acc[2];
#pragma unroll
        for (int q = 0; q < 2; ++q) { acc[q][0] = 0.f; acc[q][1] = 0.f; acc[q][2] = 0.f; acc[q][3] = 0.f; }
#pragma unroll
        for (int kt = 0; kt < 4; ++kt) {
            int abyte = (l15 * 256 + kt * 64 + kg * 16) ^ ((l15 & 7) << 4);
            s16x8 a = *(const s16x8*)((const char*)ets + abyte);
#pragma unroll
            for (int q = 0; q < 2; ++q) {
                int col = (w * 2 + q) * 16 + l15;
                s16x8 b = *(const s16x8*)(Woep + ((size_t)((kt * 128 + col) * 4 + kg)) * 8);
                acc[q] = mfma16(a, b, acc[q]);
            }
        }
#pragma unroll
        for (int q = 0; q < 2; ++q) {
            int col = (w * 2 + q) * 16 + l15;
            float bb = boe[col];
#pragma unroll
            for (int i = 0; i < 4; ++i) {
                int rr = kg * 4 + i;
                size_t idx = (size_t)(e0 + rr) * 128 + col;
                eout[idx] = (eaf[rr * 129 + col] + acc[q][i] + bb) * BNS;
            }
        }
    }
}

// Node attention: one 64-lane wave per node, CSR gather, no atomics. e_t & Vh bf16.
__global__ __launch_bounds__(64) void k_nattn(const int* __restrict__ offs, const int* __restrict__ csr,
                                              const int* __restrict__ ei, const float* __restrict__ sc,
                                              const unsigned short* __restrict__ e_t,
                                              const unsigned short* __restrict__ Vh,
                                              float* __restrict__ wV, float* __restrict__ rowV) {
    int n = blockIdx.x;
    int lane = threadIdx.x;
    int beg = offs[n], end = offs[n + 1];
    int h = lane & 7, es = lane >> 3;
    float m = -1e30f;
    for (int i = beg + es; i < end; i += 8) {
        int e = csr[i];
        m = fmaxf(m, sc[(size_t)e * 8 + h]);
    }
#pragma unroll
    for (int off = 8; off < 64; off <<= 1) m = fmaxf(m, __shfl_xor(m, off));
    float dsum = 0.0f;
    for (int i = beg + es; i < end; i += 8) {
        int e = csr[i];
        dsum += expf(sc[(size_t)e * 8 + h] - m);
    }
#pragma unroll
    for (int off = 8; off < 64; off <<= 1) dsum += __shfl_xor(dsum, off);
    float inv_d = 1.0f / (dsum + 1e-16f);

    int c0 = lane, c1 = lane + 64;
    int h0 = c0 >> 4, h1 = c1 >> 4;
    float m0 = __shfl(m, h0), m1 = __shfl(m, h1);
    float id0 = __shfl(inv_d, h0), id1 = __shfl(inv_d, h1);
    float av0 = 0.0f, av1 = 0.0f, ar0 = 0.0f, ar1 = 0.0f;
    for (int i = beg; i < end; ++i) {
        int e = csr[i];
        int s = ei[e];
        float a0 = expf(sc[(size_t)e * 8 + h0] - m0) * id0;
        float a1 = expf(sc[(size_t)e * 8 + h1] - m1) * id1;
        av0 += b2f(Vh[(size_t)s * 128 + c0]) * a0;
        av1 += b2f(Vh[(size_t)s * 128 + c1]) * a1;
        ar0 += b2f(e_t[(size_t)e * 128 + c0]) * a0;
        ar1 += b2f(e_t[(size_t)e * 128 + c1]) * a1;
    }
    wV[(size_t)n * 128 + c0] = av0;
    wV[(size_t)n * 128 + c1] = av1;
    rowV[(size_t)n * 128 + c0] = ar0;
    rowV[(size_t)n * 128 + c1] = ar1;
}

// Node post: h = wV + rowV@VeRow; deg scale; Woh; residual+BN; MLP; residual+BN. 8 nodes/block (fp32).
__global__ __launch_bounds__(256) void k_nodeB(const float* __restrict__ wV, const float* __restrict__ rowV,
                                               const float* __restrict__ VeRow, const float* __restrict__ dc,
                                               const float* __restrict__ logdeg, const float* __restrict__ x,
                                               const float* __restrict__ Woh, const float* __restrict__ boh,
                                               const float* __restrict__ W1, const float* __restrict__ b1,
                                               const float* __restrict__ W2, const float* __restrict__ b2,
                                               float* __restrict__ xout) {
    __shared__ float hs[8][128];
    __shared__ float hb[8][128];
    __shared__ float us[8][256];
    int n0 = blockIdx.x * 8;
    for (int t = threadIdx.x; t < 8 * 128; t += 256) {
        int r = t >> 7, c = t & 127;
        int n = n0 + r;
        int hh = c >> 4, d = c & 15;
        float acc = wV[(size_t)n * 128 + c];
#pragma unroll
        for (int dd = 0; dd < 16; ++dd)
            acc += rowV[(size_t)n * 128 + hh * 16 + dd] * VeRow[dd * 128 + hh * 16 + d];
        float ld = logdeg[n];
        acc = acc * (dc[c * 2 + 0] + ld * dc[c * 2 + 1]);
        hs[r][c] = acc;
    }
    __syncthreads();
    int col = threadIdx.x & 127, half = threadIdx.x >> 7;
    {
        float acc[4];
        float bb = boh[col];
#pragma unroll
        for (int r = 0; r < 4; ++r) acc[r] = bb;
        for (int k = 0; k < 128; ++k) {
            float w = Woh[k * 128 + col];
#pragma unroll
            for (int r = 0; r < 4; ++r) acc[r] += hs[half * 4 + r][k] * w;
        }
#pragma unroll
        for (int r = 0; r < 4; ++r) {
            int n = n0 + half * 4 + r;
            float xv = x[(size_t)n * 128 + col];
            hb[half * 4 + r][col] = (xv + acc[r]) * BNS;
        }
    }
    __syncthreads();
    {
        float acc[8];
        float bb = b1[threadIdx.x];
#pragma unroll
        for (int r = 0; r < 8; ++r) acc[r] = bb;
        for (int k = 0; k < 128; ++k) {
            float w = W1[k * 256 + threadIdx.x];
#pragma unroll
            for (int r = 0; r < 8; ++r) acc[r] += hb[r][k] * w;
        }
#pragma unroll
        for (int r = 0; r < 8; ++r) us[r][threadIdx.x] = fmaxf(acc[r], 0.0f);
    }
    __syncthreads();
    {
        float acc[4];
        float bb = b2[col];
#pragma unroll
        for (int r = 0; r < 4; ++r) acc[r] = bb;
        for (int k = 0; k < 256; ++k) {
            float w = W2[k * 128 + col];
#pragma unroll
            for (int r = 0; r < 4; ++r) acc[r] += us[half * 4 + r][k] * w;
        }
#pragma unroll
        for (int r = 0; r < 4; ++r) {
            int n = n0 + half * 4 + r;
            xout[(size_t)n * 128 + col] = (hb[half * 4 + r][col] + acc[r]) * BNS;
        }
    }
}

// ---------------- host launch ----------------

extern "C" void kernel_launch(void* const* d_in, const int* in_sizes, int n_in,
                              void* d_out, int out_size, void* d_ws, size_t ws_size,
                              hipStream_t stream) {
    (void)in_sizes; (void)n_in; (void)out_size; (void)ws_size;
    const float* x_in0  = (const float*)d_in[0];
    const int*   ei     = (const int*)d_in[1];
    const float* ea_in0 = (const float*)d_in[2];
    const float* Wq = (const float*)d_in[3];
    const float* bq = (const float*)d_in[4];
    const float* Wk = (const float*)d_in[5];
    const float* Wv = (const float*)d_in[6];
    const float* We = (const float*)d_in[7];
    const float* be = (const float*)d_in[8];
    const float* Aw = (const float*)d_in[9];
    const float* VeRow = (const float*)d_in[10];
    const float* Woh = (const float*)d_in[11];
    const float* boh = (const float*)d_in[12];
    const float* Woe = (const float*)d_in[13];
    const float* boe = (const float*)d_in[14];
    const float* dc  = (const float*)d_in[15];
    const float* W1 = (const float*)d_in[16];
    const float* b1 = (const float*)d_in[17];
    const float* W2 = (const float*)d_in[18];
    const float* b2 = (const float*)d_in[19];

    char* ws = (char*)d_ws;
    size_t off = 0;
    auto alloc = [&](size_t bytes) { void* p = ws + off; off = (off + bytes + 255) & ~(size_t)255; return p; };
    int*   deg    = (int*)alloc((size_t)NN * 4);
    int*   cursor = (int*)alloc((size_t)NN * 4);
    int*   offs   = (int*)alloc((size_t)(NN + 1) * 4);
    int*   csr    = (int*)alloc((size_t)NE * 4);
    float* logdeg = (float*)alloc((size_t)NN * 4);
    unsigned short* Qh = (unsigned short*)alloc((size_t)NN * 128 * 2);
    unsigned short* Kh = (unsigned short*)alloc((size_t)NN * 128 * 2);
    unsigned short* Vh = (unsigned short*)alloc((size_t)NN * 128 * 2);
    unsigned short* e_t = (unsigned short*)alloc((size_t)NE * 128 * 2);
    float* sc     = (float*)alloc((size_t)NE * 8 * 4);
    float* wV     = (float*)alloc((size_t)NN * 128 * 4);
    float* rowV   = (float*)alloc((size_t)NN * 128 * 4);
    short* Wep    = (short*)alloc((size_t)2 * 128 * 256 * 2);
    short* Woep   = (short*)alloc((size_t)2 * 128 * 128 * 2);

    float* out_x = (float*)d_out;
    float* out_e = out_x + (size_t)NN * 128;

    hipError_t err;
    err = hipMemsetAsync(deg, 0, (size_t)NN * 4, stream); (void)err;
    err = hipMemsetAsync(cursor, 0, (size_t)NN * 4, stream); (void)err;

    k_deg<<<(NE + 255) / 256, 256, 0, stream>>>(ei, deg);
    k_scan<<<1, 1024, 0, stream>>>(deg, offs);
    k_fill<<<(NE + 255) / 256, 256, 0, stream>>>(ei, offs, cursor, csr);
    k_logdeg<<<(NN + 255) / 256, 256, 0, stream>>>(deg, logdeg);

    k_pack<<<(128 * 256 + 255) / 256, 256, 0, stream>>>(We, 256, Wep);
    k_pack<<<(128 * 256 + 255) / 256, 256, 0, stream>>>(We + 128 * 256, 256, Wep + 128 * 256);
    k_pack<<<(128 * 128 + 255) / 256, 256, 0, stream>>>(Woe, 128, Woep);
    k_pack<<<(128 * 128 + 255) / 256, 256, 0, stream>>>(Woe + 128 * 128, 128, Woep + 128 * 128);

    for (int l = 0; l < 2; ++l) {
        const float* x_l  = (l == 0) ? x_in0 : out_x;
        const float* ea_l = (l == 0) ? ea_in0 : out_e;
        const float* Wq_l = Wq + (size_t)l * 128 * 128;
        const float* bq_l = bq + (size_t)l * 128;
        const float* Wk_l = Wk + (size_t)l * 128 * 128;
        const float* Wv_l = Wv + (size_t)l * 128 * 128;
        const short* Wep_l = Wep + (size_t)l * 128 * 256;
        const float* be_l = be + (size_t)l * 256;
        const float* Aw_l = Aw + (size_t)l * 16 * 8;
        const float* VeRow_l = VeRow + (size_t)l * 16 * 8 * 16;
        const float* Woh_l = Woh + (size_t)l * 128 * 128;
        const float* boh_l = boh + (size_t)l * 128;
        const short* Woep_l = Woep + (size_t)l * 128 * 128;
        const float* boe_l = boe + (size_t)l * 128;
        const float* dc_l  = dc + (size_t)l * 128 * 2;
        const float* W1_l = W1 + (size_t)l * 128 * 256;
        const float* b1_l = b1 + (size_t)l * 256;
        const float* W2_l = W2 + (size_t)l * 256 * 128;
        const float* b2_l = b2 + (size_t)l * 128;

        k_qkv<<<NN / 8, 256, 0, stream>>>(x_l, Wq_l, bq_l, Wk_l, Wv_l, Qh, Kh, Vh);
        k_edgeA<<<NE / 16, 256, 0, stream>>>(ea_l, ei, Wep_l, be_l, Aw_l, Qh, Kh, e_t, sc,
                                             Woep_l, boe_l, out_e);
        k_nattn<<<NN, 64, 0, stream>>>(offs, csr, ei, sc, e_t, Vh, wV, rowV);
        k_nodeB<<<NN / 8, 256, 0, stream>>>(wV, rowV, VeRow_l, dc_l, logdeg, x_l,
                                            Woh_l, boh_l, W1_l, b1_l, W2_l, b2_l, out_x);
    }
}

// Round 5
// 2277.760 us; speedup vs baseline: 1.0368x; 1.0368x over previous
//
#include <hip/hip_runtime.h>

#define NN 50000
#define NE 800000
#define CLAMPV 5.0f
#define BNS 0.9999950000374997f
#define EPKS 132   // int stride of packed Ep rows

typedef __attribute__((ext_vector_type(8))) short s16x8;
typedef __attribute__((ext_vector_type(8))) __bf16 bf16x8;
typedef __attribute__((ext_vector_type(4))) float f32x4;

__device__ inline f32x4 mfma16(s16x8 a, s16x8 b, f32x4 c) {
    return __builtin_amdgcn_mfma_f32_16x16x32_bf16(
        __builtin_bit_cast(bf16x8, a), __builtin_bit_cast(bf16x8, b), c, 0, 0, 0);
}

__device__ inline unsigned short bf16r(float f) {
    unsigned u = __builtin_bit_cast(unsigned, f);
    return (unsigned short)((u + 0x7FFFu + ((u >> 16) & 1u)) >> 16);
}

__device__ inline int pk2(float a, float b) {
    return (int)(unsigned)bf16r(a) | ((int)(unsigned)bf16r(b) << 16);
}

__device__ inline float b2f(unsigned short u) {
    return __builtin_bit_cast(float, (unsigned)u << 16);
}

// ---------------- degree / CSR build ----------------

__global__ __launch_bounds__(256) void k_deg(const int* __restrict__ ei, int* __restrict__ deg) {
    int e = blockIdx.x * 256 + threadIdx.x;
    if (e < NE) atomicAdd(&deg[ei[NE + e]], 1);
}

__global__ __launch_bounds__(1024) void k_scan(const int* __restrict__ deg, int* __restrict__ offs) {
    __shared__ int sm[1024];
    __shared__ int carry;
    if (threadIdx.x == 0) { carry = 0; offs[0] = 0; }
    __syncthreads();
    for (int base = 0; base < NN; base += 1024) {
        int i = base + threadIdx.x;
        int v = (i < NN) ? deg[i] : 0;
        sm[threadIdx.x] = v;
        __syncthreads();
        for (int s = 1; s < 1024; s <<= 1) {
            int t = (threadIdx.x >= s) ? sm[threadIdx.x - s] : 0;
            __syncthreads();
            sm[threadIdx.x] += t;
            __syncthreads();
        }
        if (i < NN) offs[i + 1] = carry + sm[threadIdx.x];
        __syncthreads();
        if (threadIdx.x == 0) carry += sm[1023];
        __syncthreads();
    }
}

__global__ __launch_bounds__(256) void k_fill(const int* __restrict__ ei, const int* __restrict__ offs,
                                              int* __restrict__ cursor, int* __restrict__ csr) {
    int e = blockIdx.x * 256 + threadIdx.x;
    if (e < NE) {
        int d = ei[NE + e];
        int pos = offs[d] + atomicAdd(&cursor[d], 1);
        csr[pos] = e;
    }
}

__global__ __launch_bounds__(256) void k_logdeg(const int* __restrict__ deg, float* __restrict__ logdeg) {
    int i = blockIdx.x * 256 + threadIdx.x;
    if (i < NN) logdeg[i] = logf((float)deg[i] + 1.0f);
}

// Pack fp32 weight W[k][col] into MFMA B-fragment order:
// out[((kt*ncol + col)*4 + kg)*8 + j] = bf16(W[(kt*32 + kg*8 + j)*ncol + col])
__global__ __launch_bounds__(256) void k_pack(const float* __restrict__ W, int ncol, short* __restrict__ out) {
    int idx = blockIdx.x * 256 + threadIdx.x;
    if (idx >= 128 * ncol) return;
    int j = idx & 7; int t = idx >> 3; int kg = t & 3; t >>= 2;
    int col = t % ncol; int kt = t / ncol;
    int k = kt * 32 + kg * 8 + j;
    float v = W[k * ncol + col];
    out[idx] = (short)bf16r(v);
}

// ---------------- per-layer kernels ----------------

// Q/K/V: 8 nodes/block, 256 threads, bf16 packed outputs.
__global__ __launch_bounds__(256) void k_qkv(const float* __restrict__ x,
                                             const float* __restrict__ Wq, const float* __restrict__ bq,
                                             const float* __restrict__ Wk, const float* __restrict__ Wv,
                                             unsigned short* __restrict__ Qh, unsigned short* __restrict__ Kh,
                                             unsigned short* __restrict__ Vh) {
    __shared__ float xs[8][128];
    int n0 = blockIdx.x * 8;
    {
        int row = threadIdx.x >> 5, c4 = (threadIdx.x & 31) * 4;
        *(float4*)&xs[row][c4] = *(const float4*)(x + (size_t)(n0 + row) * 128 + c4);
    }
    __syncthreads();
    int c2 = (threadIdx.x & 63) * 2, rg = threadIdx.x >> 6;
    float2 bqv = *(const float2*)(bq + c2);
    float a[3][2][2];
    a[0][0][0] = bqv.x; a[0][0][1] = bqv.y; a[0][1][0] = bqv.x; a[0][1][1] = bqv.y;
    a[1][0][0] = 0.f; a[1][0][1] = 0.f; a[1][1][0] = 0.f; a[1][1][1] = 0.f;
    a[2][0][0] = 0.f; a[2][0][1] = 0.f; a[2][1][0] = 0.f; a[2][1][1] = 0.f;
    for (int k = 0; k < 128; ++k) {
        float x0 = xs[rg * 2][k], x1 = xs[rg * 2 + 1][k];
        float2 wq = *(const float2*)(Wq + k * 128 + c2);
        float2 wk = *(const float2*)(Wk + k * 128 + c2);
        float2 wv = *(const float2*)(Wv + k * 128 + c2);
        a[0][0][0] += x0 * wq.x; a[0][0][1] += x0 * wq.y; a[0][1][0] += x1 * wq.x; a[0][1][1] += x1 * wq.y;
        a[1][0][0] += x0 * wk.x; a[1][0][1] += x0 * wk.y; a[1][1][0] += x1 * wk.x; a[1][1][1] += x1 * wk.y;
        a[2][0][0] += x0 * wv.x; a[2][0][1] += x0 * wv.y; a[2][1][0] += x1 * wv.x; a[2][1][1] += x1 * wv.y;
    }
#pragma unroll
    for (int rr = 0; rr < 2; ++rr) {
        size_t n = (size_t)(n0 + rg * 2 + rr);
        int cw = c2 >> 1;
        ((int*)Qh)[n * 64 + cw] = pk2(a[0][rr][0], a[0][rr][1]);
        ((int*)Kh)[n * 64 + cw] = pk2(a[1][rr][0], a[1][rr][1]);
        ((int*)Vh)[n * 64 + cw] = pk2(a[2][rr][0], a[2][rr][1]);
    }
}

// Fused edge kernel: Ep GEMM -> elementwise (e_t, sc) -> e_out GEMM with residual.
// 16 edges/block, 4 waves. IN_F32: layer-0 (f32 ea in, bf16 e out); else bf16 in, f32 out.
template<bool IN_F32>
__global__ __launch_bounds__(256) void k_edgeA(const void* __restrict__ ea_, const int* __restrict__ ei,
                                               const short* __restrict__ Wep, const float* __restrict__ be,
                                               const float* __restrict__ Aw,
                                               const unsigned short* __restrict__ Qh,
                                               const unsigned short* __restrict__ Kh,
                                               unsigned short* __restrict__ e_t, float* __restrict__ sc,
                                               const short* __restrict__ Woep, const float* __restrict__ boe,
                                               void* __restrict__ eout_) {
    __shared__ short eas[16 * 128];          // bf16 ea tile, XOR-swizzled (4 KB)
    __shared__ int epk[16 * EPKS];           // packed (E_w,E_b) bf16 pairs (8.4 KB)
    __shared__ short ets[16 * 128];          // bf16 e_t tile, XOR-swizzled (4 KB)
    const float* eaf = (const float*)ea_;
    const unsigned short* eab = (const unsigned short*)ea_;
    unsigned short* eout_b = (unsigned short*)eout_;
    float* eout_f = (float*)eout_;

    int e0 = blockIdx.x * 16;
    int t = threadIdx.x;
    int r = t >> 4, ci = t & 15;
    {   // phase 1: stage ea -> bf16 swizzled
        int4 pkv;
        if (IN_F32) {
            const float4* src = (const float4*)(eaf + (size_t)(e0 + r) * 128 + ci * 8);
            float4 v0 = src[0], v1 = src[1];
            pkv.x = pk2(v0.x, v0.y); pkv.y = pk2(v0.z, v0.w);
            pkv.z = pk2(v1.x, v1.y); pkv.w = pk2(v1.z, v1.w);
        } else {
            pkv = *(const int4*)(eab + (size_t)(e0 + r) * 128 + ci * 8);
        }
        int byte = (r * 256 + ci * 16) ^ ((r & 7) << 4);
        *(int4*)((char*)eas + byte) = pkv;
    }
    __syncthreads();
    int lane = t & 63, w = t >> 6;
    int l15 = lane & 15, kg = lane >> 4;
    {   // phase 2: Ep = eas @ We + be (16x256) -> packed bf16 pairs
        f32x4 acc[4];
#pragma unroll
        for (int q = 0; q < 4; ++q) { acc[q][0] = 0.f; acc[q][1] = 0.f; acc[q][2] = 0.f; acc[q][3] = 0.f; }
#pragma unroll
        for (int kt = 0; kt < 4; ++kt) {
            int abyte = (l15 * 256 + kt * 64 + kg * 16) ^ ((l15 & 7) << 4);
            s16x8 a = *(const s16x8*)((const char*)eas + abyte);
#pragma unroll
            for (int q = 0; q < 4; ++q) {
                int col = (w * 4 + q) * 16 + l15;
                s16x8 b = *(const s16x8*)(Wep + ((size_t)((kt * 256 + col) * 4 + kg)) * 8);
                acc[q] = mfma16(a, b, acc[q]);
            }
        }
        // cols (w*4+q)*16+l15: q=2p -> E_w of head 2w+p at d=l15; q=2p+1 -> E_b
#pragma unroll
        for (int p = 0; p < 2; ++p) {
            int colw = 64 * w + 32 * p + l15;
            float bw = be[colw], bb = be[colw + 16];
#pragma unroll
            for (int i = 0; i < 4; ++i) {
                int row = kg * 4 + i;
                epk[row * EPKS + (2 * w + p) * 16 + l15] = pk2(acc[2 * p][i] + bw, acc[2 * p + 1][i] + bb);
            }
        }
    }
    __syncthreads();
    {   // phase 3: elementwise — thread t: edge r, head hh=ci>>1, d-slice dbase..dbase+7
        int e = e0 + r;
        int si = ei[e], di = ei[NE + e];
        union { int4 v; unsigned short us[8]; } ku, qu;
        ku.v = *(const int4*)(Kh + (size_t)si * 128 + ci * 8);
        qu.v = *(const int4*)(Qh + (size_t)di * 128 + ci * 8);
        int hh = ci >> 1, dbase = (ci & 1) * 8;
        const int* eprow = epk + r * EPKS + hh * 16 + dbase;
        float p = 0.f;
        float etv[8];
#pragma unroll
        for (int j = 0; j < 8; ++j) {
            int pr = eprow[j];
            float ew = b2f((unsigned short)pr);
            float ebv = b2f((unsigned short)((unsigned)pr >> 16));
            float kq = b2f(ku.us[j]) + b2f(qu.us[j]);
            float sv = kq * ew;
            float ss = (sv > 0.f) ? sqrtf(sv) : ((sv < 0.f) ? -sqrtf(-sv) : 0.f);
            float et = fmaxf(ss + ebv, 0.f);
            etv[j] = et;
            p += et * Aw[(dbase + j) * 8 + hh];
        }
        int4 pkv;
        pkv.x = pk2(etv[0], etv[1]); pkv.y = pk2(etv[2], etv[3]);
        pkv.z = pk2(etv[4], etv[5]); pkv.w = pk2(etv[6], etv[7]);
        *(int4*)(e_t + (size_t)e * 128 + ci * 8) = pkv;
        int byte = (r * 256 + ci * 16) ^ ((r & 7) << 4);
        *(int4*)((char*)ets + byte) = pkv;
        p += __shfl_xor(p, 1);
        if ((ci & 1) == 0) {
            float s = fminf(fmaxf(p, -CLAMPV), CLAMPV);
            sc[(size_t)e * 8 + hh] = s;
        }
    }
    __syncthreads();
    {   // phase 4: e_out = (ea + ets @ Woe + boe) * BNS  (16x128)
        f32x4 acc[2];
#pragma unroll
        for (int q = 0; q < 2; ++q) { acc[q][0] = 0.f; acc[q][1] = 0.f; acc[q][2] = 0.f; acc[q][3] = 0.f; }
#pragma unroll
        for (int kt = 0; kt < 4; ++kt) {
            int abyte = (l15 * 256 + kt * 64 + kg * 16) ^ ((l15 & 7) << 4);
            s16x8 a = *(const s16x8*)((const char*)ets + abyte);
#pragma unroll
            for (int q = 0; q < 2; ++q) {
                int col = (w * 2 + q) * 16 + l15;
                s16x8 b = *(const s16x8*)(Woep + ((size_t)((kt * 128 + col) * 4 + kg)) * 8);
                acc[q] = mfma16(a, b, acc[q]);
            }
        }
#pragma unroll
        for (int q = 0; q < 2; ++q) {
            int col = (w * 2 + q) * 16 + l15;
            float bb = boe[col];
#pragma unroll
            for (int i = 0; i < 4; ++i) {
                int rr = kg * 4 + i;
                size_t idx = (size_t)(e0 + rr) * 128 + col;
                float res = IN_F32 ? eaf[idx] : b2f(eab[idx]);   // L2-hot re-read
                float v = (res + acc[q][i] + bb) * BNS;
                if (IN_F32) eout_b[idx] = bf16r(v);
                else        eout_f[idx] = v;
            }
        }
    }
}

// Node attention: one 64-lane wave per node, CSR gather, no atomics.
// Paired columns: lane owns cols (2*lane, 2*lane+1) — same head, one int load each for Vh/e_t.
__global__ __launch_bounds__(64) void k_nattn(const int* __restrict__ offs, const int* __restrict__ csr,
                                              const int* __restrict__ ei, const float* __restrict__ sc,
                                              const unsigned short* __restrict__ e_t,
                                              const unsigned short* __restrict__ Vh,
                                              float* __restrict__ wV, float* __restrict__ rowV) {
    int n = blockIdx.x;
    int lane = threadIdx.x;
    int beg = offs[n], end = offs[n + 1];
    int h = lane & 7, es = lane >> 3;
    float m = -1e30f;
    for (int i = beg + es; i < end; i += 8) {
        int e = csr[i];
        m = fmaxf(m, sc[(size_t)e * 8 + h]);
    }
#pragma unroll
    for (int off = 8; off < 64; off <<= 1) m = fmaxf(m, __shfl_xor(m, off));
    float dsum = 0.0f;
    for (int i = beg + es; i < end; i += 8) {
        int e = csr[i];
        dsum += expf(sc[(size_t)e * 8 + h] - m);
    }
#pragma unroll
    for (int off = 8; off < 64; off <<= 1) dsum += __shfl_xor(dsum, off);
    float inv_d = 1.0f / (dsum + 1e-16f);

    int hv = lane >> 3;                    // head of cols (2*lane, 2*lane+1)
    float mv = __shfl(m, hv);
    float idv = __shfl(inv_d, hv);
    float av0 = 0.0f, av1 = 0.0f, ar0 = 0.0f, ar1 = 0.0f;
    for (int i = beg; i < end; ++i) {
        int e = csr[i];
        int s = ei[e];
        float a = expf(sc[(size_t)e * 8 + hv] - mv) * idv;
        int v = ((const int*)Vh)[(size_t)s * 64 + lane];
        int u = ((const int*)e_t)[(size_t)e * 64 + lane];
        av0 += b2f((unsigned short)v) * a;
        av1 += b2f((unsigned short)((unsigned)v >> 16)) * a;
        ar0 += b2f((unsigned short)u) * a;
        ar1 += b2f((unsigned short)((unsigned)u >> 16)) * a;
    }
    *(float2*)(wV + (size_t)n * 128 + 2 * lane)   = make_float2(av0, av1);
    *(float2*)(rowV + (size_t)n * 128 + 2 * lane) = make_float2(ar0, ar1);
}

// Node post: h = wV + rowV@VeRow; deg scale; Woh; residual+BN; MLP; residual+BN. 8 nodes/block (fp32).
__global__ __launch_bounds__(256) void k_nodeB(const float* __restrict__ wV, const float* __restrict__ rowV,
                                               const float* __restrict__ VeRow, const float* __restrict__ dc,
                                               const float* __restrict__ logdeg, const float* __restrict__ x,
                                               const float* __restrict__ Woh, const float* __restrict__ boh,
                                               const float* __restrict__ W1, const float* __restrict__ b1,
                                               const float* __restrict__ W2, const float* __restrict__ b2,
                                               float* __restrict__ xout) {
    __shared__ float hs[8][128];
    __shared__ float hb[8][128];
    __shared__ float us[8][256];
    int n0 = blockIdx.x * 8;
    for (int t = threadIdx.x; t < 8 * 128; t += 256) {
        int r = t >> 7, c = t & 127;
        int n = n0 + r;
        int hh = c >> 4, d = c & 15;
        float acc = wV[(size_t)n * 128 + c];
#pragma unroll
        for (int dd = 0; dd < 16; ++dd)
            acc += rowV[(size_t)n * 128 + hh * 16 + dd] * VeRow[dd * 128 + hh * 16 + d];
        float ld = logdeg[n];
        acc = acc * (dc[c * 2 + 0] + ld * dc[c * 2 + 1]);
        hs[r][c] = acc;
    }
    __syncthreads();
    int col = threadIdx.x & 127, half = threadIdx.x >> 7;
    {
        float acc[4];
        float bb = boh[col];
#pragma unroll
        for (int r = 0; r < 4; ++r) acc[r] = bb;
        for (int k = 0; k < 128; ++k) {
            float w = Woh[k * 128 + col];
#pragma unroll
            for (int r = 0; r < 4; ++r) acc[r] += hs[half * 4 + r][k] * w;
        }
#pragma unroll
        for (int r = 0; r < 4; ++r) {
            int n = n0 + half * 4 + r;
            float xv = x[(size_t)n * 128 + col];
            hb[half * 4 + r][col] = (xv + acc[r]) * BNS;
        }
    }
    __syncthreads();
    {
        float acc[8];
        float bb = b1[threadIdx.x];
#pragma unroll
        for (int r = 0; r < 8; ++r) acc[r] = bb;
        for (int k = 0; k < 128; ++k) {
            float w = W1[k * 256 + threadIdx.x];
#pragma unroll
            for (int r = 0; r < 8; ++r) acc[r] += hb[r][k] * w;
        }
#pragma unroll
        for (int r = 0; r < 8; ++r) us[r][threadIdx.x] = fmaxf(acc[r], 0.0f);
    }
    __syncthreads();
    {
        float acc[4];
        float bb = b2[col];
#pragma unroll
        for (int r = 0; r < 4; ++r) acc[r] = bb;
        for (int k = 0; k < 256; ++k) {
            float w = W2[k * 128 + col];
#pragma unroll
            for (int r = 0; r < 4; ++r) acc[r] += us[half * 4 + r][k] * w;
        }
#pragma unroll
        for (int r = 0; r < 4; ++r) {
            int n = n0 + half * 4 + r;
            xout[(size_t)n * 128 + col] = (hb[half * 4 + r][col] + acc[r]) * BNS;
        }
    }
}

// ---------------- host launch ----------------

extern "C" void kernel_launch(void* const* d_in, const int* in_sizes, int n_in,
                              void* d_out, int out_size, void* d_ws, size_t ws_size,
                              hipStream_t stream) {
    (void)in_sizes; (void)n_in; (void)out_size; (void)ws_size;
    const float* x_in0  = (const float*)d_in[0];
    const int*   ei     = (const int*)d_in[1];
    const float* ea_in0 = (const float*)d_in[2];
    const float* Wq = (const float*)d_in[3];
    const float* bq = (const float*)d_in[4];
    const float* Wk = (const float*)d_in[5];
    const float* Wv = (const float*)d_in[6];
    const float* We = (const float*)d_in[7];
    const float* be = (const float*)d_in[8];
    const float* Aw = (const float*)d_in[9];
    const float* VeRow = (const float*)d_in[10];
    const float* Woh = (const float*)d_in[11];
    const float* boh = (const float*)d_in[12];
    const float* Woe = (const float*)d_in[13];
    const float* boe = (const float*)d_in[14];
    const float* dc  = (const float*)d_in[15];
    const float* W1 = (const float*)d_in[16];
    const float* b1 = (const float*)d_in[17];
    const float* W2 = (const float*)d_in[18];
    const float* b2 = (const float*)d_in[19];

    char* ws = (char*)d_ws;
    size_t off = 0;
    auto alloc = [&](size_t bytes) { void* p = ws + off; off = (off + bytes + 255) & ~(size_t)255; return p; };
    int*   deg    = (int*)alloc((size_t)NN * 4);
    int*   cursor = (int*)alloc((size_t)NN * 4);
    int*   offs   = (int*)alloc((size_t)(NN + 1) * 4);
    int*   csr    = (int*)alloc((size_t)NE * 4);
    float* logdeg = (float*)alloc((size_t)NN * 4);
    unsigned short* Qh = (unsigned short*)alloc((size_t)NN * 128 * 2);
    unsigned short* Kh = (unsigned short*)alloc((size_t)NN * 128 * 2);
    unsigned short* Vh = (unsigned short*)alloc((size_t)NN * 128 * 2);
    unsigned short* e_t = (unsigned short*)alloc((size_t)NE * 128 * 2);
    unsigned short* ea_bf = (unsigned short*)alloc((size_t)NE * 128 * 2);
    float* sc     = (float*)alloc((size_t)NE * 8 * 4);
    float* wV     = (float*)alloc((size_t)NN * 128 * 4);
    float* rowV   = (float*)alloc((size_t)NN * 128 * 4);
    short* Wep    = (short*)alloc((size_t)2 * 128 * 256 * 2);
    short* Woep   = (short*)alloc((size_t)2 * 128 * 128 * 2);

    float* out_x = (float*)d_out;
    float* out_e = out_x + (size_t)NN * 128;

    hipError_t err;
    err = hipMemsetAsync(deg, 0, (size_t)NN * 4, stream); (void)err;
    err = hipMemsetAsync(cursor, 0, (size_t)NN * 4, stream); (void)err;

    k_deg<<<(NE + 255) / 256, 256, 0, stream>>>(ei, deg);
    k_scan<<<1, 1024, 0, stream>>>(deg, offs);
    k_fill<<<(NE + 255) / 256, 256, 0, stream>>>(ei, offs, cursor, csr);
    k_logdeg<<<(NN + 255) / 256, 256, 0, stream>>>(deg, logdeg);

    k_pack<<<(128 * 256 + 255) / 256, 256, 0, stream>>>(We, 256, Wep);
    k_pack<<<(128 * 256 + 255) / 256, 256, 0, stream>>>(We + 128 * 256, 256, Wep + 128 * 256);
    k_pack<<<(128 * 128 + 255) / 256, 256, 0, stream>>>(Woe, 128, Woep);
    k_pack<<<(128 * 128 + 255) / 256, 256, 0, stream>>>(Woe + 128 * 128, 128, Woep + 128 * 128);

    for (int l = 0; l < 2; ++l) {
        const float* x_l  = (l == 0) ? x_in0 : out_x;
        const float* Wq_l = Wq + (size_t)l * 128 * 128;
        const float* bq_l = bq + (size_t)l * 128;
        const float* Wk_l = Wk + (size_t)l * 128 * 128;
        const float* Wv_l = Wv + (size_t)l * 128 * 128;
        const short* Wep_l = Wep + (size_t)l * 128 * 256;
        const float* be_l = be + (size_t)l * 256;
        const float* Aw_l = Aw + (size_t)l * 16 * 8;
        const float* VeRow_l = VeRow + (size_t)l * 16 * 8 * 16;
        const float* Woh_l = Woh + (size_t)l * 128 * 128;
        const float* boh_l = boh + (size_t)l * 128;
        const short* Woep_l = Woep + (size_t)l * 128 * 128;
        const float* boe_l = boe + (size_t)l * 128;
        const float* dc_l  = dc + (size_t)l * 128 * 2;
        const float* W1_l = W1 + (size_t)l * 128 * 256;
        const float* b1_l = b1 + (size_t)l * 256;
        const float* W2_l = W2 + (size_t)l * 256 * 128;
        const float* b2_l = b2 + (size_t)l * 128;

        k_qkv<<<NN / 8, 256, 0, stream>>>(x_l, Wq_l, bq_l, Wk_l, Wv_l, Qh, Kh, Vh);
        if (l == 0) {
            // f32 ea in -> bf16 e out (inter-layer transport)
            k_edgeA<true><<<NE / 16, 256, 0, stream>>>(ea_in0, ei, Wep_l, be_l, Aw_l, Qh, Kh,
                                                       e_t, sc, Woep_l, boe_l, ea_bf);
        } else {
            // bf16 ea in -> f32 e out (final output)
            k_edgeA<false><<<NE / 16, 256, 0, stream>>>(ea_bf, ei, Wep_l, be_l, Aw_l, Qh, Kh,
                                                        e_t, sc, Woep_l, boe_l, out_e);
        }
        k_nattn<<<NN, 64, 0, stream>>>(offs, csr, ei, sc, e_t, Vh, wV, rowV);
        k_nodeB<<<NN / 8, 256, 0, stream>>>(wV, rowV, VeRow_l, dc_l, logdeg, x_l,
                                            Woh_l, boh_l, W1_l, b1_l, W2_l, b2_l, out_x);
    }
}

// Round 6
// 2226.627 us; speedup vs baseline: 1.0606x; 1.0230x over previous
//
#include <hip/hip_runtime.h>

#define NN 50000
#define NE 800000
#define CLAMPV 5.0f
#define BNS 0.9999950000374997f
#define EPKS 132   // int stride of packed Ep rows

typedef __attribute__((ext_vector_type(8))) short s16x8;
typedef __attribute__((ext_vector_type(8))) __bf16 bf16x8;
typedef __attribute__((ext_vector_type(4))) float f32x4;

__device__ inline f32x4 mfma16(s16x8 a, s16x8 b, f32x4 c) {
    return __builtin_amdgcn_mfma_f32_16x16x32_bf16(
        __builtin_bit_cast(bf16x8, a), __builtin_bit_cast(bf16x8, b), c, 0, 0, 0);
}

__device__ inline unsigned short bf16r(float f) {
    unsigned u = __builtin_bit_cast(unsigned, f);
    return (unsigned short)((u + 0x7FFFu + ((u >> 16) & 1u)) >> 16);
}

__device__ inline int pk2(float a, float b) {
    return (int)(unsigned)bf16r(a) | ((int)(unsigned)bf16r(b) << 16);
}

__device__ inline float b2f(unsigned short u) {
    return __builtin_bit_cast(float, (unsigned)u << 16);
}

// ---------------- degree / CSR build ----------------

__global__ __launch_bounds__(256) void k_deg(const int* __restrict__ ei, int* __restrict__ deg) {
    int e = blockIdx.x * 256 + threadIdx.x;
    if (e < NE) atomicAdd(&deg[ei[NE + e]], 1);
}

__global__ __launch_bounds__(1024) void k_scan(const int* __restrict__ deg, int* __restrict__ offs) {
    __shared__ int sm[1024];
    __shared__ int carry;
    if (threadIdx.x == 0) { carry = 0; offs[0] = 0; }
    __syncthreads();
    for (int base = 0; base < NN; base += 1024) {
        int i = base + threadIdx.x;
        int v = (i < NN) ? deg[i] : 0;
        sm[threadIdx.x] = v;
        __syncthreads();
        for (int s = 1; s < 1024; s <<= 1) {
            int t = (threadIdx.x >= s) ? sm[threadIdx.x - s] : 0;
            __syncthreads();
            sm[threadIdx.x] += t;
            __syncthreads();
        }
        if (i < NN) offs[i + 1] = carry + sm[threadIdx.x];
        __syncthreads();
        if (threadIdx.x == 0) carry += sm[1023];
        __syncthreads();
    }
}

// csr_src[pos] = src node of the edge in CSR slot pos; epos[e] = CSR slot of edge e.
__global__ __launch_bounds__(256) void k_fill(const int* __restrict__ ei, const int* __restrict__ offs,
                                              int* __restrict__ cursor, int* __restrict__ csr_src,
                                              int* __restrict__ epos) {
    int e = blockIdx.x * 256 + threadIdx.x;
    if (e < NE) {
        int d = ei[NE + e];
        int pos = offs[d] + atomicAdd(&cursor[d], 1);
        csr_src[pos] = ei[e];
        epos[e] = pos;
    }
}

__global__ __launch_bounds__(256) void k_logdeg(const int* __restrict__ deg, float* __restrict__ logdeg) {
    int i = blockIdx.x * 256 + threadIdx.x;
    if (i < NN) logdeg[i] = logf((float)deg[i] + 1.0f);
}

// Pack fp32 weight W[k][col] into MFMA B-fragment order:
// out[((kt*ncol + col)*4 + kg)*8 + j] = bf16(W[(kt*32 + kg*8 + j)*ncol + col])
__global__ __launch_bounds__(256) void k_pack(const float* __restrict__ W, int ncol, short* __restrict__ out) {
    int idx = blockIdx.x * 256 + threadIdx.x;
    if (idx >= 128 * ncol) return;
    int j = idx & 7; int t = idx >> 3; int kg = t & 3; t >>= 2;
    int col = t % ncol; int kt = t / ncol;
    int k = kt * 32 + kg * 8 + j;
    float v = W[k * ncol + col];
    out[idx] = (short)bf16r(v);
}

// ---------------- per-layer kernels ----------------

// Q/K/V: 8 nodes/block, 256 threads, bf16 packed outputs.
__global__ __launch_bounds__(256) void k_qkv(const float* __restrict__ x,
                                             const float* __restrict__ Wq, const float* __restrict__ bq,
                                             const float* __restrict__ Wk, const float* __restrict__ Wv,
                                             unsigned short* __restrict__ Qh, unsigned short* __restrict__ Kh,
                                             unsigned short* __restrict__ Vh) {
    __shared__ float xs[8][128];
    int n0 = blockIdx.x * 8;
    {
        int row = threadIdx.x >> 5, c4 = (threadIdx.x & 31) * 4;
        *(float4*)&xs[row][c4] = *(const float4*)(x + (size_t)(n0 + row) * 128 + c4);
    }
    __syncthreads();
    int c2 = (threadIdx.x & 63) * 2, rg = threadIdx.x >> 6;
    float2 bqv = *(const float2*)(bq + c2);
    float a[3][2][2];
    a[0][0][0] = bqv.x; a[0][0][1] = bqv.y; a[0][1][0] = bqv.x; a[0][1][1] = bqv.y;
    a[1][0][0] = 0.f; a[1][0][1] = 0.f; a[1][1][0] = 0.f; a[1][1][1] = 0.f;
    a[2][0][0] = 0.f; a[2][0][1] = 0.f; a[2][1][0] = 0.f; a[2][1][1] = 0.f;
    for (int k = 0; k < 128; ++k) {
        float x0 = xs[rg * 2][k], x1 = xs[rg * 2 + 1][k];
        float2 wq = *(const float2*)(Wq + k * 128 + c2);
        float2 wk = *(const float2*)(Wk + k * 128 + c2);
        float2 wv = *(const float2*)(Wv + k * 128 + c2);
        a[0][0][0] += x0 * wq.x; a[0][0][1] += x0 * wq.y; a[0][1][0] += x1 * wq.x; a[0][1][1] += x1 * wq.y;
        a[1][0][0] += x0 * wk.x; a[1][0][1] += x0 * wk.y; a[1][1][0] += x1 * wk.x; a[1][1][1] += x1 * wk.y;
        a[2][0][0] += x0 * wv.x; a[2][0][1] += x0 * wv.y; a[2][1][0] += x1 * wv.x; a[2][1][1] += x1 * wv.y;
    }
#pragma unroll
    for (int rr = 0; rr < 2; ++rr) {
        size_t n = (size_t)(n0 + rg * 2 + rr);
        int cw = c2 >> 1;
        ((int*)Qh)[n * 64 + cw] = pk2(a[0][rr][0], a[0][rr][1]);
        ((int*)Kh)[n * 64 + cw] = pk2(a[1][rr][0], a[1][rr][1]);
        ((int*)Vh)[n * 64 + cw] = pk2(a[2][rr][0], a[2][rr][1]);
    }
}

// Fused edge kernel: Ep GEMM -> elementwise (e_t, sc -> CSR order) -> e_out GEMM with residual.
// 16 edges/block, 4 waves. IN_F32: layer-0 (f32 ea in, bf16 e out); else bf16 in, f32 out.
template<bool IN_F32>
__global__ __launch_bounds__(256) void k_edgeA(const void* __restrict__ ea_, const int* __restrict__ ei,
                                               const int* __restrict__ epos,
                                               const short* __restrict__ Wep, const float* __restrict__ be,
                                               const float* __restrict__ Aw,
                                               const unsigned short* __restrict__ Qh,
                                               const unsigned short* __restrict__ Kh,
                                               unsigned short* __restrict__ e_t, float* __restrict__ sc,
                                               const short* __restrict__ Woep, const float* __restrict__ boe,
                                               void* __restrict__ eout_) {
    __shared__ short eas[16 * 128];          // bf16 ea tile, XOR-swizzled (4 KB)
    __shared__ int epk[16 * EPKS];           // packed (E_w,E_b) bf16 pairs (8.4 KB)
    __shared__ short ets[16 * 128];          // bf16 e_t tile, XOR-swizzled (4 KB)
    const float* eaf = (const float*)ea_;
    const unsigned short* eab = (const unsigned short*)ea_;
    unsigned short* eout_b = (unsigned short*)eout_;
    float* eout_f = (float*)eout_;

    int e0 = blockIdx.x * 16;
    int t = threadIdx.x;
    int r = t >> 4, ci = t & 15;

    // ---- T14: issue gather loads FIRST; consumed in phase 3 after two barriers ----
    int e = e0 + r;
    int si = ei[e], di = ei[NE + e];
    int pos = epos[e];
    union { int4 v; unsigned short us[8]; } ku, qu;
    ku.v = *(const int4*)(Kh + (size_t)si * 128 + ci * 8);
    qu.v = *(const int4*)(Qh + (size_t)di * 128 + ci * 8);

    {   // phase 1: stage ea -> bf16 swizzled
        int4 pkv;
        if (IN_F32) {
            const float4* src = (const float4*)(eaf + (size_t)e * 128 + ci * 8);
            float4 v0 = src[0], v1 = src[1];
            pkv.x = pk2(v0.x, v0.y); pkv.y = pk2(v0.z, v0.w);
            pkv.z = pk2(v1.x, v1.y); pkv.w = pk2(v1.z, v1.w);
        } else {
            pkv = *(const int4*)(eab + (size_t)e * 128 + ci * 8);
        }
        int byte = (r * 256 + ci * 16) ^ ((r & 7) << 4);
        *(int4*)((char*)eas + byte) = pkv;
    }
    __syncthreads();
    int lane = t & 63, w = t >> 6;
    int l15 = lane & 15, kg = lane >> 4;
    {   // phase 2: Ep = eas @ We + be (16x256) -> packed bf16 pairs
        f32x4 acc[4];
#pragma unroll
        for (int q = 0; q < 4; ++q) { acc[q][0] = 0.f; acc[q][1] = 0.f; acc[q][2] = 0.f; acc[q][3] = 0.f; }
#pragma unroll
        for (int kt = 0; kt < 4; ++kt) {
            int abyte = (l15 * 256 + kt * 64 + kg * 16) ^ ((l15 & 7) << 4);
            s16x8 a = *(const s16x8*)((const char*)eas + abyte);
#pragma unroll
            for (int q = 0; q < 4; ++q) {
                int col = (w * 4 + q) * 16 + l15;
                s16x8 b = *(const s16x8*)(Wep + ((size_t)((kt * 256 + col) * 4 + kg)) * 8);
                acc[q] = mfma16(a, b, acc[q]);
            }
        }
        // cols (w*4+q)*16+l15: q=2p -> E_w of head 2w+p at d=l15; q=2p+1 -> E_b
#pragma unroll
        for (int p = 0; p < 2; ++p) {
            int colw = 64 * w + 32 * p + l15;
            float bw = be[colw], bb = be[colw + 16];
#pragma unroll
            for (int i = 0; i < 4; ++i) {
                int row = kg * 4 + i;
                epk[row * EPKS + (2 * w + p) * 16 + l15] = pk2(acc[2 * p][i] + bw, acc[2 * p + 1][i] + bb);
            }
        }
    }
    __syncthreads();
    {   // phase 3: elementwise — thread t: edge r, head hh=ci>>1, d-slice dbase..dbase+7
        int hh = ci >> 1, dbase = (ci & 1) * 8;
        const int4* eprow4 = (const int4*)(epk + r * EPKS + ci * 8);
        int4 w0 = eprow4[0], w1 = eprow4[1];
        int prs[8] = {w0.x, w0.y, w0.z, w0.w, w1.x, w1.y, w1.z, w1.w};
        float p = 0.f;
        float etv[8];
#pragma unroll
        for (int j = 0; j < 8; ++j) {
            int pr = prs[j];
            float ew = b2f((unsigned short)pr);
            float ebv = b2f((unsigned short)((unsigned)pr >> 16));
            float kq = b2f(ku.us[j]) + b2f(qu.us[j]);
            float sv = kq * ew;
            float ss = (sv > 0.f) ? sqrtf(sv) : ((sv < 0.f) ? -sqrtf(-sv) : 0.f);
            float et = fmaxf(ss + ebv, 0.f);
            etv[j] = et;
            p += et * Aw[(dbase + j) * 8 + hh];
        }
        int4 pkv;
        pkv.x = pk2(etv[0], etv[1]); pkv.y = pk2(etv[2], etv[3]);
        pkv.z = pk2(etv[4], etv[5]); pkv.w = pk2(etv[6], etv[7]);
        *(int4*)(e_t + (size_t)pos * 128 + ci * 8) = pkv;     // scatter to CSR slot
        int byte = (r * 256 + ci * 16) ^ ((r & 7) << 4);
        *(int4*)((char*)ets + byte) = pkv;
        p += __shfl_xor(p, 1);
        if ((ci & 1) == 0) {
            float s = fminf(fmaxf(p, -CLAMPV), CLAMPV);
            sc[(size_t)pos * 8 + hh] = s;                      // scatter to CSR slot
        }
    }
    __syncthreads();
    {   // phase 4: e_out = (ea + ets @ Woe + boe) * BNS  (16x128); residual from eas LDS
        f32x4 acc[2];
#pragma unroll
        for (int q = 0; q < 2; ++q) { acc[q][0] = 0.f; acc[q][1] = 0.f; acc[q][2] = 0.f; acc[q][3] = 0.f; }
#pragma unroll
        for (int kt = 0; kt < 4; ++kt) {
            int abyte = (l15 * 256 + kt * 64 + kg * 16) ^ ((l15 & 7) << 4);
            s16x8 a = *(const s16x8*)((const char*)ets + abyte);
#pragma unroll
            for (int q = 0; q < 2; ++q) {
                int col = (w * 2 + q) * 16 + l15;
                s16x8 b = *(const s16x8*)(Woep + ((size_t)((kt * 128 + col) * 4 + kg)) * 8);
                acc[q] = mfma16(a, b, acc[q]);
            }
        }
#pragma unroll
        for (int q = 0; q < 2; ++q) {
            int col = (w * 2 + q) * 16 + l15;
            float bb = boe[col];
#pragma unroll
            for (int i = 0; i < 4; ++i) {
                int rr = kg * 4 + i;
                int rbyte = (rr * 256 + col * 2) ^ ((rr & 7) << 4);
                float res = b2f(*(const unsigned short*)((const char*)eas + rbyte));
                size_t idx = (size_t)(e0 + rr) * 128 + col;
                float v = (res + acc[q][i] + bb) * BNS;
                if (IN_F32) eout_b[idx] = bf16r(v);
                else        eout_f[idx] = v;
            }
        }
    }
}

// Node attention: one 64-lane wave per node. sc/e_t are in CSR order -> fully coalesced;
// only the Vh gather (L2-resident) is random.
__global__ __launch_bounds__(64) void k_nattn(const int* __restrict__ offs, const int* __restrict__ csr_src,
                                              const float* __restrict__ sc,
                                              const unsigned short* __restrict__ e_t,
                                              const unsigned short* __restrict__ Vh,
                                              float* __restrict__ wV, float* __restrict__ rowV) {
    int n = blockIdx.x;
    int lane = threadIdx.x;
    int beg = offs[n], end = offs[n + 1];
    int h = lane & 7, es = lane >> 3;
    float m = -1e30f;
    for (int i = beg + es; i < end; i += 8)
        m = fmaxf(m, sc[(size_t)i * 8 + h]);
#pragma unroll
    for (int off = 8; off < 64; off <<= 1) m = fmaxf(m, __shfl_xor(m, off));
    float dsum = 0.0f;
    for (int i = beg + es; i < end; i += 8)
        dsum += expf(sc[(size_t)i * 8 + h] - m);
#pragma unroll
    for (int off = 8; off < 64; off <<= 1) dsum += __shfl_xor(dsum, off);
    float inv_d = 1.0f / (dsum + 1e-16f);

    int hv = lane >> 3;                    // head of cols (2*lane, 2*lane+1)
    float mv = __shfl(m, hv);
    float idv = __shfl(inv_d, hv);
    float av0 = 0.0f, av1 = 0.0f, ar0 = 0.0f, ar1 = 0.0f;
    for (int i = beg; i < end; ++i) {
        float a = expf(sc[(size_t)i * 8 + hv] - mv) * idv;
        int s = csr_src[i];
        int v = ((const int*)Vh)[(size_t)s * 64 + lane];
        int u = ((const int*)e_t)[(size_t)i * 64 + lane];
        av0 += b2f((unsigned short)v) * a;
        av1 += b2f((unsigned short)((unsigned)v >> 16)) * a;
        ar0 += b2f((unsigned short)u) * a;
        ar1 += b2f((unsigned short)((unsigned)u >> 16)) * a;
    }
    *(float2*)(wV + (size_t)n * 128 + 2 * lane)   = make_float2(av0, av1);
    *(float2*)(rowV + (size_t)n * 128 + 2 * lane) = make_float2(ar0, ar1);
}

// Node post: h = wV + rowV@VeRow; deg scale; Woh; residual+BN; MLP; residual+BN. 8 nodes/block (fp32).
__global__ __launch_bounds__(256) void k_nodeB(const float* __restrict__ wV, const float* __restrict__ rowV,
                                               const float* __restrict__ VeRow, const float* __restrict__ dc,
                                               const float* __restrict__ logdeg, const float* __restrict__ x,
                                               const float* __restrict__ Woh, const float* __restrict__ boh,
                                               const float* __restrict__ W1, const float* __restrict__ b1,
                                               const float* __restrict__ W2, const float* __restrict__ b2,
                                               float* __restrict__ xout) {
    __shared__ float hs[8][128];
    __shared__ float hb[8][128];
    __shared__ float us[8][256];
    int n0 = blockIdx.x * 8;
    for (int t = threadIdx.x; t < 8 * 128; t += 256) {
        int r = t >> 7, c = t & 127;
        int n = n0 + r;
        int hh = c >> 4, d = c & 15;
        float acc = wV[(size_t)n * 128 + c];
#pragma unroll
        for (int dd = 0; dd < 16; ++dd)
            acc += rowV[(size_t)n * 128 + hh * 16 + dd] * VeRow[dd * 128 + hh * 16 + d];
        float ld = logdeg[n];
        acc = acc * (dc[c * 2 + 0] + ld * dc[c * 2 + 1]);
        hs[r][c] = acc;
    }
    __syncthreads();
    int col = threadIdx.x & 127, half = threadIdx.x >> 7;
    {
        float acc[4];
        float bb = boh[col];
#pragma unroll
        for (int r = 0; r < 4; ++r) acc[r] = bb;
        for (int k = 0; k < 128; ++k) {
            float w = Woh[k * 128 + col];
#pragma unroll
            for (int r = 0; r < 4; ++r) acc[r] += hs[half * 4 + r][k] * w;
        }
#pragma unroll
        for (int r = 0; r < 4; ++r) {
            int n = n0 + half * 4 + r;
            float xv = x[(size_t)n * 128 + col];
            hb[half * 4 + r][col] = (xv + acc[r]) * BNS;
        }
    }
    __syncthreads();
    {
        float acc[8];
        float bb = b1[threadIdx.x];
#pragma unroll
        for (int r = 0; r < 8; ++r) acc[r] = bb;
        for (int k = 0; k < 128; ++k) {
            float w = W1[k * 256 + threadIdx.x];
#pragma unroll
            for (int r = 0; r < 8; ++r) acc[r] += hb[r][k] * w;
        }
#pragma unroll
        for (int r = 0; r < 8; ++r) us[r][threadIdx.x] = fmaxf(acc[r], 0.0f);
    }
    __syncthreads();
    {
        float acc[4];
        float bb = b2[col];
#pragma unroll
        for (int r = 0; r < 4; ++r) acc[r] = bb;
        for (int k = 0; k < 256; ++k) {
            float w = W2[k * 128 + col];
#pragma unroll
            for (int r = 0; r < 4; ++r) acc[r] += us[half * 4 + r][k] * w;
        }
#pragma unroll
        for (int r = 0; r < 4; ++r) {
            int n = n0 + half * 4 + r;
            xout[(size_t)n * 128 + col] = (hb[half * 4 + r][col] + acc[r]) * BNS;
        }
    }
}

// ---------------- host launch ----------------

extern "C" void kernel_launch(void* const* d_in, const int* in_sizes, int n_in,
                              void* d_out, int out_size, void* d_ws, size_t ws_size,
                              hipStream_t stream) {
    (void)in_sizes; (void)n_in; (void)out_size; (void)ws_size;
    const float* x_in0  = (const float*)d_in[0];
    const int*   ei     = (const int*)d_in[1];
    const float* ea_in0 = (const float*)d_in[2];
    const float* Wq = (const float*)d_in[3];
    const float* bq = (const float*)d_in[4];
    const float* Wk = (const float*)d_in[5];
    const float* Wv = (const float*)d_in[6];
    const float* We = (const float*)d_in[7];
    const float* be = (const float*)d_in[8];
    const float* Aw = (const float*)d_in[9];
    const float* VeRow = (const float*)d_in[10];
    const float* Woh = (const float*)d_in[11];
    const float* boh = (const float*)d_in[12];
    const float* Woe = (const float*)d_in[13];
    const float* boe = (const float*)d_in[14];
    const float* dc  = (const float*)d_in[15];
    const float* W1 = (const float*)d_in[16];
    const float* b1 = (const float*)d_in[17];
    const float* W2 = (const float*)d_in[18];
    const float* b2 = (const float*)d_in[19];

    char* ws = (char*)d_ws;
    size_t off = 0;
    auto alloc = [&](size_t bytes) { void* p = ws + off; off = (off + bytes + 255) & ~(size_t)255; return p; };
    int*   deg    = (int*)alloc((size_t)NN * 4);
    int*   cursor = (int*)alloc((size_t)NN * 4);
    int*   offs   = (int*)alloc((size_t)(NN + 1) * 4);
    int*   csr_src= (int*)alloc((size_t)NE * 4);
    int*   epos   = (int*)alloc((size_t)NE * 4);
    float* logdeg = (float*)alloc((size_t)NN * 4);
    unsigned short* Qh = (unsigned short*)alloc((size_t)NN * 128 * 2);
    unsigned short* Kh = (unsigned short*)alloc((size_t)NN * 128 * 2);
    unsigned short* Vh = (unsigned short*)alloc((size_t)NN * 128 * 2);
    unsigned short* e_t = (unsigned short*)alloc((size_t)NE * 128 * 2);
    unsigned short* ea_bf = (unsigned short*)alloc((size_t)NE * 128 * 2);
    float* sc     = (float*)alloc((size_t)NE * 8 * 4);
    float* wV     = (float*)alloc((size_t)NN * 128 * 4);
    float* rowV   = (float*)alloc((size_t)NN * 128 * 4);
    short* Wep    = (short*)alloc((size_t)2 * 128 * 256 * 2);
    short* Woep   = (short*)alloc((size_t)2 * 128 * 128 * 2);

    float* out_x = (float*)d_out;
    float* out_e = out_x + (size_t)NN * 128;

    hipError_t err;
    err = hipMemsetAsync(deg, 0, (size_t)NN * 4, stream); (void)err;
    err = hipMemsetAsync(cursor, 0, (size_t)NN * 4, stream); (void)err;

    k_deg<<<(NE + 255) / 256, 256, 0, stream>>>(ei, deg);
    k_scan<<<1, 1024, 0, stream>>>(deg, offs);
    k_fill<<<(NE + 255) / 256, 256, 0, stream>>>(ei, offs, cursor, csr_src, epos);
    k_logdeg<<<(NN + 255) / 256, 256, 0, stream>>>(deg, logdeg);

    k_pack<<<(128 * 256 + 255) / 256, 256, 0, stream>>>(We, 256, Wep);
    k_pack<<<(128 * 256 + 255) / 256, 256, 0, stream>>>(We + 128 * 256, 256, Wep + 128 * 256);
    k_pack<<<(128 * 128 + 255) / 256, 256, 0, stream>>>(Woe, 128, Woep);
    k_pack<<<(128 * 128 + 255) / 256, 256, 0, stream>>>(Woe + 128 * 128, 128, Woep + 128 * 128);

    for (int l = 0; l < 2; ++l) {
        const float* x_l  = (l == 0) ? x_in0 : out_x;
        const float* Wq_l = Wq + (size_t)l * 128 * 128;
        const float* bq_l = bq + (size_t)l * 128;
        const float* Wk_l = Wk + (size_t)l * 128 * 128;
        const float* Wv_l = Wv + (size_t)l * 128 * 128;
        const short* Wep_l = Wep + (size_t)l * 128 * 256;
        const float* be_l = be + (size_t)l * 256;
        const float* Aw_l = Aw + (size_t)l * 16 * 8;
        const float* VeRow_l = VeRow + (size_t)l * 16 * 8 * 16;
        const float* Woh_l = Woh + (size_t)l * 128 * 128;
        const float* boh_l = boh + (size_t)l * 128;
        const short* Woep_l = Woep + (size_t)l * 128 * 128;
        const float* boe_l = boe + (size_t)l * 128;
        const float* dc_l  = dc + (size_t)l * 128 * 2;
        const float* W1_l = W1 + (size_t)l * 128 * 256;
        const float* b1_l = b1 + (size_t)l * 256;
        const float* W2_l = W2 + (size_t)l * 256 * 128;
        const float* b2_l = b2 + (size_t)l * 128;

        k_qkv<<<NN / 8, 256, 0, stream>>>(x_l, Wq_l, bq_l, Wk_l, Wv_l, Qh, Kh, Vh);
        if (l == 0) {
            k_edgeA<true><<<NE / 16, 256, 0, stream>>>(ea_in0, ei, epos, Wep_l, be_l, Aw_l, Qh, Kh,
                                                       e_t, sc, Woep_l, boe_l, ea_bf);
        } else {
            k_edgeA<false><<<NE / 16, 256, 0, stream>>>(ea_bf, ei, epos, Wep_l, be_l, Aw_l, Qh, Kh,
                                                        e_t, sc, Woep_l, boe_l, out_e);
        }
        k_nattn<<<NN, 64, 0, stream>>>(offs, csr_src, sc, e_t, Vh, wV, rowV);
        k_nodeB<<<NN / 8, 256, 0, stream>>>(wV, rowV, VeRow_l, dc_l, logdeg, x_l,
                                            Woh_l, boh_l, W1_l, b1_l, W2_l, b2_l, out_x);
    }
}

// Round 7
// 1430.298 us; speedup vs baseline: 1.6511x; 1.5568x over previous
//
#include <hip/hip_runtime.h>

#define NN 50000
#define NE 800000
#define CLAMPV 5.0f
#define BNS 0.9999950000374997f
#define EPKS 132   // int stride of packed Ep rows

typedef __attribute__((ext_vector_type(8))) short s16x8;
typedef __attribute__((ext_vector_type(8))) __bf16 bf16x8;
typedef __attribute__((ext_vector_type(4))) float f32x4;

__device__ inline f32x4 mfma16(s16x8 a, s16x8 b, f32x4 c) {
    return __builtin_amdgcn_mfma_f32_16x16x32_bf16(
        __builtin_bit_cast(bf16x8, a), __builtin_bit_cast(bf16x8, b), c, 0, 0, 0);
}

__device__ inline unsigned short bf16r(float f) {
    unsigned u = __builtin_bit_cast(unsigned, f);
    return (unsigned short)((u + 0x7FFFu + ((u >> 16) & 1u)) >> 16);
}

__device__ inline int pk2(float a, float b) {
    return (int)(unsigned)bf16r(a) | ((int)(unsigned)bf16r(b) << 16);
}

__device__ inline float b2f(unsigned short u) {
    return __builtin_bit_cast(float, (unsigned)u << 16);
}

// ---------------- degree / CSR build ----------------

__global__ __launch_bounds__(256) void k_deg(const int* __restrict__ ei, int* __restrict__ deg) {
    int e = blockIdx.x * 256 + threadIdx.x;
    if (e < NE) atomicAdd(&deg[ei[NE + e]], 1);
}

__global__ __launch_bounds__(1024) void k_scan(const int* __restrict__ deg, int* __restrict__ offs) {
    __shared__ int sm[1024];
    __shared__ int carry;
    if (threadIdx.x == 0) { carry = 0; offs[0] = 0; }
    __syncthreads();
    for (int base = 0; base < NN; base += 1024) {
        int i = base + threadIdx.x;
        int v = (i < NN) ? deg[i] : 0;
        sm[threadIdx.x] = v;
        __syncthreads();
        for (int s = 1; s < 1024; s <<= 1) {
            int t = (threadIdx.x >= s) ? sm[threadIdx.x - s] : 0;
            __syncthreads();
            sm[threadIdx.x] += t;
            __syncthreads();
        }
        if (i < NN) offs[i + 1] = carry + sm[threadIdx.x];
        __syncthreads();
        if (threadIdx.x == 0) carry += sm[1023];
        __syncthreads();
    }
}

// csr_src[pos] = src node of the edge in CSR slot pos; epos[e] = CSR slot of edge e.
__global__ __launch_bounds__(256) void k_fill(const int* __restrict__ ei, const int* __restrict__ offs,
                                              int* __restrict__ cursor, int* __restrict__ csr_src,
                                              int* __restrict__ epos) {
    int e = blockIdx.x * 256 + threadIdx.x;
    if (e < NE) {
        int d = ei[NE + e];
        int pos = offs[d] + atomicAdd(&cursor[d], 1);
        csr_src[pos] = ei[e];
        epos[e] = pos;
    }
}

__global__ __launch_bounds__(256) void k_logdeg(const int* __restrict__ deg, float* __restrict__ logdeg) {
    int i = blockIdx.x * 256 + threadIdx.x;
    if (i < NN) logdeg[i] = logf((float)deg[i] + 1.0f);
}

// Pack fp32 weight W[k][col] into MFMA B-fragment order:
// out[((kt*ncol + col)*4 + kg)*8 + j] = bf16(W[(kt*32 + kg*8 + j)*ncol + col])
__global__ __launch_bounds__(256) void k_pack(const float* __restrict__ W, int ncol, short* __restrict__ out) {
    int idx = blockIdx.x * 256 + threadIdx.x;
    if (idx >= 128 * ncol) return;
    int j = idx & 7; int t = idx >> 3; int kg = t & 3; t >>= 2;
    int col = t % ncol; int kt = t / ncol;
    int k = kt * 32 + kg * 8 + j;
    float v = W[k * ncol + col];
    out[idx] = (short)bf16r(v);
}

// ---------------- per-layer kernels ----------------

// Q/K/V via MFMA: 64 nodes/block, 512 threads (8 waves). Wave w owns col-tile w (16 cols)
// of ALL THREE output matrices; weights read once per block.
__global__ __launch_bounds__(512) void k_qkv(const float* __restrict__ x,
                                             const short* __restrict__ Wqp, const float* __restrict__ bq,
                                             const short* __restrict__ Wkp, const short* __restrict__ Wvp,
                                             unsigned short* __restrict__ Qh, unsigned short* __restrict__ Kh,
                                             unsigned short* __restrict__ Vh) {
    __shared__ short xsw[64 * 128];   // bf16, XOR-swizzled
    int t = threadIdx.x;
    int ci = t & 15, r0 = t >> 4;     // r0 in 0..31
    int n0 = blockIdx.x * 64;
    for (int rr = r0; rr < 64; rr += 32) {
        int n = n0 + rr;
        int4 pkv = make_int4(0, 0, 0, 0);
        if (n < NN) {
            const float4* src = (const float4*)(x + (size_t)n * 128 + ci * 8);
            float4 v0 = src[0], v1 = src[1];
            pkv.x = pk2(v0.x, v0.y); pkv.y = pk2(v0.z, v0.w);
            pkv.z = pk2(v1.x, v1.y); pkv.w = pk2(v1.z, v1.w);
        }
        int byte = (rr * 256 + ci * 16) ^ ((rr & 7) << 4);
        *(int4*)((char*)xsw + byte) = pkv;
    }
    __syncthreads();
    int lane = t & 63, w = t >> 6;
    int l15 = lane & 15, kg = lane >> 4;
    f32x4 acc[4][3];
#pragma unroll
    for (int m = 0; m < 4; ++m)
#pragma unroll
        for (int q = 0; q < 3; ++q) { acc[m][q][0] = 0.f; acc[m][q][1] = 0.f; acc[m][q][2] = 0.f; acc[m][q][3] = 0.f; }
    int col = w * 16 + l15;
#pragma unroll
    for (int kt = 0; kt < 4; ++kt) {
        s16x8 a[4];
#pragma unroll
        for (int m = 0; m < 4; ++m) {
            int row = m * 16 + l15;
            int abyte = (row * 256 + kt * 64 + kg * 16) ^ ((l15 & 7) << 4);
            a[m] = *(const s16x8*)((const char*)xsw + abyte);
        }
        size_t bo = ((size_t)((kt * 128 + col) * 4 + kg)) * 8;
        s16x8 bqf = *(const s16x8*)(Wqp + bo);
        s16x8 bkf = *(const s16x8*)(Wkp + bo);
        s16x8 bvf = *(const s16x8*)(Wvp + bo);
#pragma unroll
        for (int m = 0; m < 4; ++m) {
            acc[m][0] = mfma16(a[m], bqf, acc[m][0]);
            acc[m][1] = mfma16(a[m], bkf, acc[m][1]);
            acc[m][2] = mfma16(a[m], bvf, acc[m][2]);
        }
    }
    float bqv = bq[col];
#pragma unroll
    for (int m = 0; m < 4; ++m)
#pragma unroll
        for (int i = 0; i < 4; ++i) {
            int n = n0 + m * 16 + kg * 4 + i;
            if (n < NN) {
                Qh[(size_t)n * 128 + col] = bf16r(acc[m][0][i] + bqv);
                Kh[(size_t)n * 128 + col] = bf16r(acc[m][1][i]);
                Vh[(size_t)n * 128 + col] = bf16r(acc[m][2][i]);
            }
        }
}

// Fused edge kernel: 64 edges/block, 512 threads (8 waves).
// Ep GEMM -> elementwise (e_t, sc -> CSR order) -> e_out GEMM with residual.
template<bool IN_F32>
__global__ __launch_bounds__(512) void k_edgeA(const void* __restrict__ ea_, const int* __restrict__ ei,
                                               const int* __restrict__ epos,
                                               const short* __restrict__ Wep, const float* __restrict__ be,
                                               const float* __restrict__ Aw,
                                               const unsigned short* __restrict__ Qh,
                                               const unsigned short* __restrict__ Kh,
                                               unsigned short* __restrict__ e_t, float* __restrict__ sc,
                                               const short* __restrict__ Woep, const float* __restrict__ boe,
                                               void* __restrict__ eout_) {
    __shared__ short eas[64 * 128];          // bf16 ea tile, XOR-swizzled (16 KB)
    __shared__ int epk[64 * EPKS];           // packed (E_w,E_b) bf16 pairs (33.8 KB)
    __shared__ short ets[64 * 128];          // bf16 e_t tile, XOR-swizzled (16 KB)
    const float* eaf = (const float*)ea_;
    const unsigned short* eab = (const unsigned short*)ea_;
    unsigned short* eout_b = (unsigned short*)eout_;
    float* eout_f = (float*)eout_;

    int e0 = blockIdx.x * 64;
    int t = threadIdx.x;
    int ci = t & 15, r0 = t >> 4;            // r0 in 0..31; thread owns edges r0 and r0+32
    int eA = e0 + r0, eB = eA + 32;
    int siA = ei[eA], diA = ei[NE + eA], posA = epos[eA];
    int siB = ei[eB], diB = ei[NE + eB], posB = epos[eB];

    {   // phase 1: stage ea -> bf16 swizzled (2 rows/thread)
#pragma unroll
        for (int h = 0; h < 2; ++h) {
            int rr = r0 + h * 32;
            int4 pkv;
            if (IN_F32) {
                const float4* src = (const float4*)(eaf + (size_t)(e0 + rr) * 128 + ci * 8);
                float4 v0 = src[0], v1 = src[1];
                pkv.x = pk2(v0.x, v0.y); pkv.y = pk2(v0.z, v0.w);
                pkv.z = pk2(v1.x, v1.y); pkv.w = pk2(v1.z, v1.w);
            } else {
                pkv = *(const int4*)(eab + (size_t)(e0 + rr) * 128 + ci * 8);
            }
            int byte = (rr * 256 + ci * 16) ^ ((rr & 7) << 4);
            *(int4*)((char*)eas + byte) = pkv;
        }
    }
    __syncthreads();
    // T14: issue K/Q gathers now — they fly under the whole phase-2 MFMA block
    union { int4 v; unsigned short us[8]; } kuA, quA, kuB, quB;
    kuA.v = *(const int4*)(Kh + (size_t)siA * 128 + ci * 8);
    quA.v = *(const int4*)(Qh + (size_t)diA * 128 + ci * 8);
    kuB.v = *(const int4*)(Kh + (size_t)siB * 128 + ci * 8);
    quB.v = *(const int4*)(Qh + (size_t)diB * 128 + ci * 8);

    int lane = t & 63, w = t >> 6;
    int l15 = lane & 15, kg = lane >> 4;
    {   // phase 2: Ep = eas(64x128) @ We(128x256) + be. Wave w owns cols [w*32, w*32+32) = head w.
        f32x4 acc[4][2];
#pragma unroll
        for (int m = 0; m < 4; ++m)
#pragma unroll
            for (int q = 0; q < 2; ++q) { acc[m][q][0] = 0.f; acc[m][q][1] = 0.f; acc[m][q][2] = 0.f; acc[m][q][3] = 0.f; }
#pragma unroll
        for (int kt = 0; kt < 4; ++kt) {
            s16x8 a[4];
#pragma unroll
            for (int m = 0; m < 4; ++m) {
                int row = m * 16 + l15;
                int abyte = (row * 256 + kt * 64 + kg * 16) ^ ((l15 & 7) << 4);
                a[m] = *(const s16x8*)((const char*)eas + abyte);
            }
#pragma unroll
            for (int q = 0; q < 2; ++q) {
                int col = w * 32 + q * 16 + l15;
                s16x8 b = *(const s16x8*)(Wep + ((size_t)((kt * 256 + col) * 4 + kg)) * 8);
#pragma unroll
                for (int m = 0; m < 4; ++m) acc[m][q] = mfma16(a[m], b, acc[m][q]);
            }
        }
        float bw = be[w * 32 + l15], bb = be[w * 32 + 16 + l15];
#pragma unroll
        for (int m = 0; m < 4; ++m)
#pragma unroll
            for (int i = 0; i < 4; ++i) {
                int row = m * 16 + kg * 4 + i;
                epk[row * EPKS + w * 16 + l15] = pk2(acc[m][0][i] + bw, acc[m][1][i] + bb);
            }
    }
    __syncthreads();
    {   // phase 3: elementwise — thread: edges r0, r0+32; head hh=ci>>1, d-slice (ci&1)*8..+7
        int hh = ci >> 1, dbase = (ci & 1) * 8;
        float aw[8];
#pragma unroll
        for (int j = 0; j < 8; ++j) aw[j] = Aw[(dbase + j) * 8 + hh];
#pragma unroll
        for (int h = 0; h < 2; ++h) {
            int r = r0 + h * 32;
            int pos = h ? posB : posA;
            const unsigned short* kus = h ? kuB.us : kuA.us;
            const unsigned short* qus = h ? quB.us : quA.us;
            const int4* eprow4 = (const int4*)(epk + r * EPKS + ci * 8);
            int4 w0 = eprow4[0], w1 = eprow4[1];
            int prs[8] = {w0.x, w0.y, w0.z, w0.w, w1.x, w1.y, w1.z, w1.w};
            float p = 0.f;
            float etv[8];
#pragma unroll
            for (int j = 0; j < 8; ++j) {
                int pr = prs[j];
                float ew = b2f((unsigned short)pr);
                float ebv = b2f((unsigned short)((unsigned)pr >> 16));
                float kq = b2f(kus[j]) + b2f(qus[j]);
                float sv = kq * ew;
                float ss = (sv > 0.f) ? sqrtf(sv) : ((sv < 0.f) ? -sqrtf(-sv) : 0.f);
                float et = fmaxf(ss + ebv, 0.f);
                etv[j] = et;
                p += et * aw[j];
            }
            int4 pkv;
            pkv.x = pk2(etv[0], etv[1]); pkv.y = pk2(etv[2], etv[3]);
            pkv.z = pk2(etv[4], etv[5]); pkv.w = pk2(etv[6], etv[7]);
            *(int4*)(e_t + (size_t)pos * 128 + ci * 8) = pkv;     // scatter to CSR slot
            int byte = (r * 256 + ci * 16) ^ ((r & 7) << 4);
            *(int4*)((char*)ets + byte) = pkv;
            p += __shfl_xor(p, 1);
            if ((ci & 1) == 0) {
                float s = fminf(fmaxf(p, -CLAMPV), CLAMPV);
                sc[(size_t)pos * 8 + hh] = s;                      // scatter to CSR slot
            }
        }
    }
    __syncthreads();
    {   // phase 4: e_out = (ea + ets(64x128) @ Woe(128x128) + boe) * BNS. Wave w owns col-tile w.
        f32x4 acc[4];
#pragma unroll
        for (int m = 0; m < 4; ++m) { acc[m][0] = 0.f; acc[m][1] = 0.f; acc[m][2] = 0.f; acc[m][3] = 0.f; }
        int col = w * 16 + l15;
#pragma unroll
        for (int kt = 0; kt < 4; ++kt) {
            s16x8 a[4];
#pragma unroll
            for (int m = 0; m < 4; ++m) {
                int row = m * 16 + l15;
                int abyte = (row * 256 + kt * 64 + kg * 16) ^ ((l15 & 7) << 4);
                a[m] = *(const s16x8*)((const char*)ets + abyte);
            }
            s16x8 b = *(const s16x8*)(Woep + ((size_t)((kt * 128 + col) * 4 + kg)) * 8);
#pragma unroll
            for (int m = 0; m < 4; ++m) acc[m] = mfma16(a[m], b, acc[m]);
        }
        float bb = boe[col];
#pragma unroll
        for (int m = 0; m < 4; ++m)
#pragma unroll
            for (int i = 0; i < 4; ++i) {
                int rr = m * 16 + kg * 4 + i;
                int rbyte = (rr * 256 + col * 2) ^ ((rr & 7) << 4);
                float res = b2f(*(const unsigned short*)((const char*)eas + rbyte));
                size_t idx = (size_t)(e0 + rr) * 128 + col;
                float v = (res + acc[m][i] + bb) * BNS;
                if (IN_F32) eout_b[idx] = bf16r(v);
                else        eout_f[idx] = v;
            }
    }
}

// Node attention: one 64-lane wave per node. sc/e_t in CSR order -> coalesced;
// only the Vh gather (L2-resident) is random.
__global__ __launch_bounds__(64) void k_nattn(const int* __restrict__ offs, const int* __restrict__ csr_src,
                                              const float* __restrict__ sc,
                                              const unsigned short* __restrict__ e_t,
                                              const unsigned short* __restrict__ Vh,
                                              float* __restrict__ wV, float* __restrict__ rowV) {
    int n = blockIdx.x;
    int lane = threadIdx.x;
    int beg = offs[n], end = offs[n + 1];
    int h = lane & 7, es = lane >> 3;
    float m = -1e30f;
    for (int i = beg + es; i < end; i += 8)
        m = fmaxf(m, sc[(size_t)i * 8 + h]);
#pragma unroll
    for (int off = 8; off < 64; off <<= 1) m = fmaxf(m, __shfl_xor(m, off));
    float dsum = 0.0f;
    for (int i = beg + es; i < end; i += 8)
        dsum += expf(sc[(size_t)i * 8 + h] - m);
#pragma unroll
    for (int off = 8; off < 64; off <<= 1) dsum += __shfl_xor(dsum, off);
    float inv_d = 1.0f / (dsum + 1e-16f);

    int hv = lane >> 3;                    // head of cols (2*lane, 2*lane+1)
    float mv = __shfl(m, hv);
    float idv = __shfl(inv_d, hv);
    float av0 = 0.0f, av1 = 0.0f, ar0 = 0.0f, ar1 = 0.0f;
    for (int i = beg; i < end; ++i) {
        float a = expf(sc[(size_t)i * 8 + hv] - mv) * idv;
        int s = csr_src[i];
        int v = ((const int*)Vh)[(size_t)s * 64 + lane];
        int u = ((const int*)e_t)[(size_t)i * 64 + lane];
        av0 += b2f((unsigned short)v) * a;
        av1 += b2f((unsigned short)((unsigned)v >> 16)) * a;
        ar0 += b2f((unsigned short)u) * a;
        ar1 += b2f((unsigned short)((unsigned)u >> 16)) * a;
    }
    *(float2*)(wV + (size_t)n * 128 + 2 * lane)   = make_float2(av0, av1);
    *(float2*)(rowV + (size_t)n * 128 + 2 * lane) = make_float2(ar0, ar1);
}

// Node post: h = wV + rowV@VeRow; deg scale; Woh; residual+BN; MLP; residual+BN. 8 nodes/block (fp32).
__global__ __launch_bounds__(256) void k_nodeB(const float* __restrict__ wV, const float* __restrict__ rowV,
                                               const float* __restrict__ VeRow, const float* __restrict__ dc,
                                               const float* __restrict__ logdeg, const float* __restrict__ x,
                                               const float* __restrict__ Woh, const float* __restrict__ boh,
                                               const float* __restrict__ W1, const float* __restrict__ b1,
                                               const float* __restrict__ W2, const float* __restrict__ b2,
                                               float* __restrict__ xout) {
    __shared__ float hs[8][128];
    __shared__ float hb[8][128];
    __shared__ float us[8][256];
    int n0 = blockIdx.x * 8;
    for (int t = threadIdx.x; t < 8 * 128; t += 256) {
        int r = t >> 7, c = t & 127;
        int n = n0 + r;
        int hh = c >> 4, d = c & 15;
        float acc = wV[(size_t)n * 128 + c];
#pragma unroll
        for (int dd = 0; dd < 16; ++dd)
            acc += rowV[(size_t)n * 128 + hh * 16 + dd] * VeRow[dd * 128 + hh * 16 + d];
        float ld = logdeg[n];
        acc = acc * (dc[c * 2 + 0] + ld * dc[c * 2 + 1]);
        hs[r][c] = acc;
    }
    __syncthreads();
    int col = threadIdx.x & 127, half = threadIdx.x >> 7;
    {
        float acc[4];
        float bb = boh[col];
#pragma unroll
        for (int r = 0; r < 4; ++r) acc[r] = bb;
        for (int k = 0; k < 128; ++k) {
            float w = Woh[k * 128 + col];
#pragma unroll
            for (int r = 0; r < 4; ++r) acc[r] += hs[half * 4 + r][k] * w;
        }
#pragma unroll
        for (int r = 0; r < 4; ++r) {
            int n = n0 + half * 4 + r;
            float xv = x[(size_t)n * 128 + col];
            hb[half * 4 + r][col] = (xv + acc[r]) * BNS;
        }
    }
    __syncthreads();
    {
        float acc[8];
        float bb = b1[threadIdx.x];
#pragma unroll
        for (int r = 0; r < 8; ++r) acc[r] = bb;
        for (int k = 0; k < 128; ++k) {
            float w = W1[k * 256 + threadIdx.x];
#pragma unroll
            for (int r = 0; r < 8; ++r) acc[r] += hb[r][k] * w;
        }
#pragma unroll
        for (int r = 0; r < 8; ++r) us[r][threadIdx.x] = fmaxf(acc[r], 0.0f);
    }
    __syncthreads();
    {
        float acc[4];
        float bb = b2[col];
#pragma unroll
        for (int r = 0; r < 4; ++r) acc[r] = bb;
        for (int k = 0; k < 256; ++k) {
            float w = W2[k * 128 + col];
#pragma unroll
            for (int r = 0; r < 4; ++r) acc[r] += us[half * 4 + r][k] * w;
        }
#pragma unroll
        for (int r = 0; r < 4; ++r) {
            int n = n0 + half * 4 + r;
            xout[(size_t)n * 128 + col] = (hb[half * 4 + r][col] + acc[r]) * BNS;
        }
    }
}

// ---------------- host launch ----------------

extern "C" void kernel_launch(void* const* d_in, const int* in_sizes, int n_in,
                              void* d_out, int out_size, void* d_ws, size_t ws_size,
                              hipStream_t stream) {
    (void)in_sizes; (void)n_in; (void)out_size; (void)ws_size;
    const float* x_in0  = (const float*)d_in[0];
    const int*   ei     = (const int*)d_in[1];
    const float* ea_in0 = (const float*)d_in[2];
    const float* Wq = (const float*)d_in[3];
    const float* bq = (const float*)d_in[4];
    const float* Wk = (const float*)d_in[5];
    const float* Wv = (const float*)d_in[6];
    const float* We = (const float*)d_in[7];
    const float* be = (const float*)d_in[8];
    const float* Aw = (const float*)d_in[9];
    const float* VeRow = (const float*)d_in[10];
    const float* Woh = (const float*)d_in[11];
    const float* boh = (const float*)d_in[12];
    const float* Woe = (const float*)d_in[13];
    const float* boe = (const float*)d_in[14];
    const float* dc  = (const float*)d_in[15];
    const float* W1 = (const float*)d_in[16];
    const float* b1 = (const float*)d_in[17];
    const float* W2 = (const float*)d_in[18];
    const float* b2 = (const float*)d_in[19];

    char* ws = (char*)d_ws;
    size_t off = 0;
    auto alloc = [&](size_t bytes) { void* p = ws + off; off = (off + bytes + 255) & ~(size_t)255; return p; };
    int*   deg    = (int*)alloc((size_t)NN * 4);
    int*   cursor = (int*)alloc((size_t)NN * 4);
    int*   offs   = (int*)alloc((size_t)(NN + 1) * 4);
    int*   csr_src= (int*)alloc((size_t)NE * 4);
    int*   epos   = (int*)alloc((size_t)NE * 4);
    float* logdeg = (float*)alloc((size_t)NN * 4);
    unsigned short* Qh = (unsigned short*)alloc((size_t)NN * 128 * 2);
    unsigned short* Kh = (unsigned short*)alloc((size_t)NN * 128 * 2);
    unsigned short* Vh = (unsigned short*)alloc((size_t)NN * 128 * 2);
    unsigned short* e_t = (unsigned short*)alloc((size_t)NE * 128 * 2);
    unsigned short* ea_bf = (unsigned short*)alloc((size_t)NE * 128 * 2);
    float* sc     = (float*)alloc((size_t)NE * 8 * 4);
    float* wV     = (float*)alloc((size_t)NN * 128 * 4);
    float* rowV   = (float*)alloc((size_t)NN * 128 * 4);
    short* Wep    = (short*)alloc((size_t)2 * 128 * 256 * 2);
    short* Woep   = (short*)alloc((size_t)2 * 128 * 128 * 2);
    short* Wqp    = (short*)alloc((size_t)2 * 128 * 128 * 2);
    short* Wkp    = (short*)alloc((size_t)2 * 128 * 128 * 2);
    short* Wvp    = (short*)alloc((size_t)2 * 128 * 128 * 2);

    float* out_x = (float*)d_out;
    float* out_e = out_x + (size_t)NN * 128;

    hipError_t err;
    err = hipMemsetAsync(deg, 0, (size_t)NN * 4, stream); (void)err;
    err = hipMemsetAsync(cursor, 0, (size_t)NN * 4, stream); (void)err;

    k_deg<<<(NE + 255) / 256, 256, 0, stream>>>(ei, deg);
    k_scan<<<1, 1024, 0, stream>>>(deg, offs);
    k_fill<<<(NE + 255) / 256, 256, 0, stream>>>(ei, offs, cursor, csr_src, epos);
    k_logdeg<<<(NN + 255) / 256, 256, 0, stream>>>(deg, logdeg);

    k_pack<<<(128 * 256 + 255) / 256, 256, 0, stream>>>(We, 256, Wep);
    k_pack<<<(128 * 256 + 255) / 256, 256, 0, stream>>>(We + 128 * 256, 256, Wep + 128 * 256);
    k_pack<<<(128 * 128 + 255) / 256, 256, 0, stream>>>(Woe, 128, Woep);
    k_pack<<<(128 * 128 + 255) / 256, 256, 0, stream>>>(Woe + 128 * 128, 128, Woep + 128 * 128);
    k_pack<<<(128 * 128 + 255) / 256, 256, 0, stream>>>(Wq, 128, Wqp);
    k_pack<<<(128 * 128 + 255) / 256, 256, 0, stream>>>(Wq + 128 * 128, 128, Wqp + 128 * 128);
    k_pack<<<(128 * 128 + 255) / 256, 256, 0, stream>>>(Wk, 128, Wkp);
    k_pack<<<(128 * 128 + 255) / 256, 256, 0, stream>>>(Wk + 128 * 128, 128, Wkp + 128 * 128);
    k_pack<<<(128 * 128 + 255) / 256, 256, 0, stream>>>(Wv, 128, Wvp);
    k_pack<<<(128 * 128 + 255) / 256, 256, 0, stream>>>(Wv + 128 * 128, 128, Wvp + 128 * 128);

    for (int l = 0; l < 2; ++l) {
        const float* x_l  = (l == 0) ? x_in0 : out_x;
        const short* Wqp_l = Wqp + (size_t)l * 128 * 128;
        const float* bq_l = bq + (size_t)l * 128;
        const short* Wkp_l = Wkp + (size_t)l * 128 * 128;
        const short* Wvp_l = Wvp + (size_t)l * 128 * 128;
        const short* Wep_l = Wep + (size_t)l * 128 * 256;
        const float* be_l = be + (size_t)l * 256;
        const float* Aw_l = Aw + (size_t)l * 16 * 8;
        const float* VeRow_l = VeRow + (size_t)l * 16 * 8 * 16;
        const float* Woh_l = Woh + (size_t)l * 128 * 128;
        const float* boh_l = boh + (size_t)l * 128;
        const short* Woep_l = Woep + (size_t)l * 128 * 128;
        const float* boe_l = boe + (size_t)l * 128;
        const float* dc_l  = dc + (size_t)l * 128 * 2;
        const float* W1_l = W1 + (size_t)l * 128 * 256;
        const float* b1_l = b1 + (size_t)l * 256;
        const float* W2_l = W2 + (size_t)l * 256 * 128;
        const float* b2_l = b2 + (size_t)l * 128;

        k_qkv<<<(NN + 63) / 64, 512, 0, stream>>>(x_l, Wqp_l, bq_l, Wkp_l, Wvp_l, Qh, Kh, Vh);
        if (l == 0) {
            k_edgeA<true><<<NE / 64, 512, 0, stream>>>(ea_in0, ei, epos, Wep_l, be_l, Aw_l, Qh, Kh,
                                                       e_t, sc, Woep_l, boe_l, ea_bf);
        } else {
            k_edgeA<false><<<NE / 64, 512, 0, stream>>>(ea_bf, ei, epos, Wep_l, be_l, Aw_l, Qh, Kh,
                                                        e_t, sc, Woep_l, boe_l, out_e);
        }
        k_nattn<<<NN, 64, 0, stream>>>(offs, csr_src, sc, e_t, Vh, wV, rowV);
        k_nodeB<<<NN / 8, 256, 0, stream>>>(wV, rowV, VeRow_l, dc_l, logdeg, x_l,
                                            Woh_l, boh_l, W1_l, b1_l, W2_l, b2_l, out_x);
    }
}

// Round 8
// 1137.029 us; speedup vs baseline: 2.0770x; 1.2579x over previous
//
#include <hip/hip_runtime.h>

#define NN 50000
#define NE 800000
#define CLAMPV 5.0f
#define BNS 0.9999950000374997f
#define EPKS 132   // int stride of packed Ep rows

typedef __attribute__((ext_vector_type(8))) short s16x8;
typedef __attribute__((ext_vector_type(8))) __bf16 bf16x8;
typedef __attribute__((ext_vector_type(4))) float f32x4;

__device__ inline f32x4 mfma16(s16x8 a, s16x8 b, f32x4 c) {
    return __builtin_amdgcn_mfma_f32_16x16x32_bf16(
        __builtin_bit_cast(bf16x8, a), __builtin_bit_cast(bf16x8, b), c, 0, 0, 0);
}

__device__ inline unsigned short bf16r(float f) {
    return __builtin_bit_cast(unsigned short, (__bf16)f);   // RNE, compiler emits v_cvt_pk_bf16_f32
}

__device__ inline int pk2(float a, float b) {
    return (int)(unsigned)bf16r(a) | ((int)(unsigned)bf16r(b) << 16);
}

__device__ inline float b2f(unsigned short u) {
    return __builtin_bit_cast(float, (unsigned)u << 16);
}

// ---------------- degree / CSR build ----------------

__global__ __launch_bounds__(256) void k_deg(const int* __restrict__ ei, int* __restrict__ deg) {
    int e = blockIdx.x * 256 + threadIdx.x;
    if (e < NE) atomicAdd(&deg[ei[NE + e]], 1);
}

__global__ __launch_bounds__(1024) void k_scan(const int* __restrict__ deg, int* __restrict__ offs) {
    __shared__ int sm[1024];
    __shared__ int carry;
    if (threadIdx.x == 0) { carry = 0; offs[0] = 0; }
    __syncthreads();
    for (int base = 0; base < NN; base += 1024) {
        int i = base + threadIdx.x;
        int v = (i < NN) ? deg[i] : 0;
        sm[threadIdx.x] = v;
        __syncthreads();
        for (int s = 1; s < 1024; s <<= 1) {
            int t = (threadIdx.x >= s) ? sm[threadIdx.x - s] : 0;
            __syncthreads();
            sm[threadIdx.x] += t;
            __syncthreads();
        }
        if (i < NN) offs[i + 1] = carry + sm[threadIdx.x];
        __syncthreads();
        if (threadIdx.x == 0) carry += sm[1023];
        __syncthreads();
    }
}

// csr_src[pos] = src node of the edge in CSR slot pos; epos[e] = CSR slot of edge e.
__global__ __launch_bounds__(256) void k_fill(const int* __restrict__ ei, const int* __restrict__ offs,
                                              int* __restrict__ cursor, int* __restrict__ csr_src,
                                              int* __restrict__ epos) {
    int e = blockIdx.x * 256 + threadIdx.x;
    if (e < NE) {
        int d = ei[NE + e];
        int pos = offs[d] + atomicAdd(&cursor[d], 1);
        csr_src[pos] = ei[e];
        epos[e] = pos;
    }
}

__global__ __launch_bounds__(256) void k_logdeg(const int* __restrict__ deg, float* __restrict__ logdeg) {
    int i = blockIdx.x * 256 + threadIdx.x;
    if (i < NN) logdeg[i] = logf((float)deg[i] + 1.0f);
}

// Pack fp32 weight W[k][col] (K x ncol) into MFMA B-fragment order:
// out[((kt*ncol + col)*4 + kg)*8 + j] = bf16(W[(kt*32 + kg*8 + j)*ncol + col])
__global__ __launch_bounds__(256) void k_packW(const float* __restrict__ W, int ncol, int total,
                                               short* __restrict__ out) {
    int idx = blockIdx.x * 256 + threadIdx.x;
    if (idx >= total) return;
    int j = idx & 7; int t = idx >> 3; int kg = t & 3; t >>= 2;
    int col = t % ncol; int kt = t / ncol;
    int k = kt * 32 + kg * 8 + j;
    out[idx] = (short)bf16r(W[k * ncol + col]);
}

// Pack VeRow (16,8,16) as a block-diagonal 128x128 B-fragment:
// M[k][c] = (k>>4 == c>>4) ? VeRow[(k&15)*128 + c] : 0
__global__ __launch_bounds__(256) void k_packVR(const float* __restrict__ VR, short* __restrict__ out) {
    int idx = blockIdx.x * 256 + threadIdx.x;
    if (idx >= 128 * 128) return;
    int j = idx & 7; int t = idx >> 3; int kg = t & 3; t >>= 2;
    int col = t & 127; int kt = t >> 7;
    int k = kt * 32 + kg * 8 + j;
    float v = ((k >> 4) == (col >> 4)) ? VR[(k & 15) * 128 + col] : 0.f;
    out[idx] = (short)bf16r(v);
}

// ---------------- per-layer kernels ----------------

// Q/K/V via MFMA: 64 nodes/block, 512 threads (8 waves).
__global__ __launch_bounds__(512) void k_qkv(const float* __restrict__ x,
                                             const short* __restrict__ Wqp, const float* __restrict__ bq,
                                             const short* __restrict__ Wkp, const short* __restrict__ Wvp,
                                             unsigned short* __restrict__ Qh, unsigned short* __restrict__ Kh,
                                             unsigned short* __restrict__ Vh) {
    __shared__ short xsw[64 * 128];   // bf16, XOR-swizzled
    int t = threadIdx.x;
    int ci = t & 15, r0 = t >> 4;     // r0 in 0..31
    int n0 = blockIdx.x * 64;
    for (int rr = r0; rr < 64; rr += 32) {
        int n = n0 + rr;
        int4 pkv = make_int4(0, 0, 0, 0);
        if (n < NN) {
            const float4* src = (const float4*)(x + (size_t)n * 128 + ci * 8);
            float4 v0 = src[0], v1 = src[1];
            pkv.x = pk2(v0.x, v0.y); pkv.y = pk2(v0.z, v0.w);
            pkv.z = pk2(v1.x, v1.y); pkv.w = pk2(v1.z, v1.w);
        }
        int byte = (rr * 256 + ci * 16) ^ ((rr & 7) << 4);
        *(int4*)((char*)xsw + byte) = pkv;
    }
    __syncthreads();
    int lane = t & 63, w = t >> 6;
    int l15 = lane & 15, kg = lane >> 4;
    f32x4 acc[4][3];
#pragma unroll
    for (int m = 0; m < 4; ++m)
#pragma unroll
        for (int q = 0; q < 3; ++q) { acc[m][q][0] = 0.f; acc[m][q][1] = 0.f; acc[m][q][2] = 0.f; acc[m][q][3] = 0.f; }
    int col = w * 16 + l15;
#pragma unroll
    for (int kt = 0; kt < 4; ++kt) {
        s16x8 a[4];
#pragma unroll
        for (int m = 0; m < 4; ++m) {
            int row = m * 16 + l15;
            int abyte = (row * 256 + kt * 64 + kg * 16) ^ ((l15 & 7) << 4);
            a[m] = *(const s16x8*)((const char*)xsw + abyte);
        }
        size_t bo = ((size_t)((kt * 128 + col) * 4 + kg)) * 8;
        s16x8 bqf = *(const s16x8*)(Wqp + bo);
        s16x8 bkf = *(const s16x8*)(Wkp + bo);
        s16x8 bvf = *(const s16x8*)(Wvp + bo);
#pragma unroll
        for (int m = 0; m < 4; ++m) {
            acc[m][0] = mfma16(a[m], bqf, acc[m][0]);
            acc[m][1] = mfma16(a[m], bkf, acc[m][1]);
            acc[m][2] = mfma16(a[m], bvf, acc[m][2]);
        }
    }
    float bqv = bq[col];
#pragma unroll
    for (int m = 0; m < 4; ++m)
#pragma unroll
        for (int i = 0; i < 4; ++i) {
            int n = n0 + m * 16 + kg * 4 + i;
            if (n < NN) {
                Qh[(size_t)n * 128 + col] = bf16r(acc[m][0][i] + bqv);
                Kh[(size_t)n * 128 + col] = bf16r(acc[m][1][i]);
                Vh[(size_t)n * 128 + col] = bf16r(acc[m][2][i]);
            }
        }
}

// Fused edge kernel: 64 edges/block, 512 threads (8 waves).
template<bool IN_F32>
__global__ __launch_bounds__(512) void k_edgeA(const void* __restrict__ ea_, const int* __restrict__ ei,
                                               const int* __restrict__ epos,
                                               const short* __restrict__ Wep, const float* __restrict__ be,
                                               const float* __restrict__ Aw,
                                               const unsigned short* __restrict__ Qh,
                                               const unsigned short* __restrict__ Kh,
                                               unsigned short* __restrict__ e_t, float* __restrict__ sc,
                                               const short* __restrict__ Woep, const float* __restrict__ boe,
                                               void* __restrict__ eout_) {
    __shared__ short eas[64 * 128];          // bf16 ea tile, XOR-swizzled (16 KB)
    __shared__ int epk[64 * EPKS];           // packed (E_w,E_b) bf16 pairs (33.8 KB)
    __shared__ short ets[64 * 128];          // bf16 e_t tile, XOR-swizzled (16 KB)
    const float* eaf = (const float*)ea_;
    const unsigned short* eab = (const unsigned short*)ea_;
    unsigned short* eout_b = (unsigned short*)eout_;
    float* eout_f = (float*)eout_;

    int e0 = blockIdx.x * 64;
    int t = threadIdx.x;
    int ci = t & 15, r0 = t >> 4;            // r0 in 0..31; thread owns edges r0 and r0+32
    int eA = e0 + r0, eB = eA + 32;
    int siA = ei[eA], diA = ei[NE + eA], posA = epos[eA];
    int siB = ei[eB], diB = ei[NE + eB], posB = epos[eB];

    {   // phase 1: stage ea -> bf16 swizzled (2 rows/thread)
#pragma unroll
        for (int h = 0; h < 2; ++h) {
            int rr = r0 + h * 32;
            int4 pkv;
            if (IN_F32) {
                const float4* src = (const float4*)(eaf + (size_t)(e0 + rr) * 128 + ci * 8);
                float4 v0 = src[0], v1 = src[1];
                pkv.x = pk2(v0.x, v0.y); pkv.y = pk2(v0.z, v0.w);
                pkv.z = pk2(v1.x, v1.y); pkv.w = pk2(v1.z, v1.w);
            } else {
                pkv = *(const int4*)(eab + (size_t)(e0 + rr) * 128 + ci * 8);
            }
            int byte = (rr * 256 + ci * 16) ^ ((rr & 7) << 4);
            *(int4*)((char*)eas + byte) = pkv;
        }
    }
    __syncthreads();
    // T14: issue K/Q gathers now — they fly under the whole phase-2 MFMA block
    union { int4 v; unsigned short us[8]; } kuA, quA, kuB, quB;
    kuA.v = *(const int4*)(Kh + (size_t)siA * 128 + ci * 8);
    quA.v = *(const int4*)(Qh + (size_t)diA * 128 + ci * 8);
    kuB.v = *(const int4*)(Kh + (size_t)siB * 128 + ci * 8);
    quB.v = *(const int4*)(Qh + (size_t)diB * 128 + ci * 8);

    int lane = t & 63, w = t >> 6;
    int l15 = lane & 15, kg = lane >> 4;
    {   // phase 2: Ep = eas(64x128) @ We(128x256) + be. Wave w owns head w's 32 cols.
        f32x4 acc[4][2];
#pragma unroll
        for (int m = 0; m < 4; ++m)
#pragma unroll
            for (int q = 0; q < 2; ++q) { acc[m][q][0] = 0.f; acc[m][q][1] = 0.f; acc[m][q][2] = 0.f; acc[m][q][3] = 0.f; }
#pragma unroll
        for (int kt = 0; kt < 4; ++kt) {
            s16x8 a[4];
#pragma unroll
            for (int m = 0; m < 4; ++m) {
                int row = m * 16 + l15;
                int abyte = (row * 256 + kt * 64 + kg * 16) ^ ((l15 & 7) << 4);
                a[m] = *(const s16x8*)((const char*)eas + abyte);
            }
#pragma unroll
            for (int q = 0; q < 2; ++q) {
                int col = w * 32 + q * 16 + l15;
                s16x8 b = *(const s16x8*)(Wep + ((size_t)((kt * 256 + col) * 4 + kg)) * 8);
#pragma unroll
                for (int m = 0; m < 4; ++m) acc[m][q] = mfma16(a[m], b, acc[m][q]);
            }
        }
        float bw = be[w * 32 + l15], bb = be[w * 32 + 16 + l15];
#pragma unroll
        for (int m = 0; m < 4; ++m)
#pragma unroll
            for (int i = 0; i < 4; ++i) {
                int row = m * 16 + kg * 4 + i;
                epk[row * EPKS + w * 16 + l15] = pk2(acc[m][0][i] + bw, acc[m][1][i] + bb);
            }
    }
    __syncthreads();
    {   // phase 3: elementwise — thread: edges r0, r0+32; head hh=ci>>1, d-slice (ci&1)*8..+7
        int hh = ci >> 1, dbase = (ci & 1) * 8;
        float aw[8];
#pragma unroll
        for (int j = 0; j < 8; ++j) aw[j] = Aw[(dbase + j) * 8 + hh];
#pragma unroll
        for (int h = 0; h < 2; ++h) {
            int r = r0 + h * 32;
            int pos = h ? posB : posA;
            const unsigned short* kus = h ? kuB.us : kuA.us;
            const unsigned short* qus = h ? quB.us : quA.us;
            const int4* eprow4 = (const int4*)(epk + r * EPKS + ci * 8);
            int4 w0 = eprow4[0], w1 = eprow4[1];
            int prs[8] = {w0.x, w0.y, w0.z, w0.w, w1.x, w1.y, w1.z, w1.w};
            float p = 0.f;
            float etv[8];
#pragma unroll
            for (int j = 0; j < 8; ++j) {
                int pr = prs[j];
                float ew = b2f((unsigned short)pr);
                float ebv = b2f((unsigned short)((unsigned)pr >> 16));
                float kq = b2f(kus[j]) + b2f(qus[j]);
                float sv = kq * ew;
                float ss = copysignf(sqrtf(fabsf(sv)), sv);   // signed_sqrt, 1 sqrt + modifiers
                float et = fmaxf(ss + ebv, 0.f);
                etv[j] = et;
                p += et * aw[j];
            }
            int4 pkv;
            pkv.x = pk2(etv[0], etv[1]); pkv.y = pk2(etv[2], etv[3]);
            pkv.z = pk2(etv[4], etv[5]); pkv.w = pk2(etv[6], etv[7]);
            *(int4*)(e_t + (size_t)pos * 128 + ci * 8) = pkv;     // scatter to CSR slot
            int byte = (r * 256 + ci * 16) ^ ((r & 7) << 4);
            *(int4*)((char*)ets + byte) = pkv;
            p += __shfl_xor(p, 1);
            if ((ci & 1) == 0) {
                float s = fminf(fmaxf(p, -CLAMPV), CLAMPV);
                sc[(size_t)pos * 8 + hh] = s;                      // scatter to CSR slot
            }
        }
    }
    __syncthreads();
    {   // phase 4: e_out = (ea + ets(64x128) @ Woe(128x128) + boe) * BNS. Wave w owns col-tile w.
        f32x4 acc[4];
#pragma unroll
        for (int m = 0; m < 4; ++m) { acc[m][0] = 0.f; acc[m][1] = 0.f; acc[m][2] = 0.f; acc[m][3] = 0.f; }
        int col = w * 16 + l15;
#pragma unroll
        for (int kt = 0; kt < 4; ++kt) {
            s16x8 a[4];
#pragma unroll
            for (int m = 0; m < 4; ++m) {
                int row = m * 16 + l15;
                int abyte = (row * 256 + kt * 64 + kg * 16) ^ ((l15 & 7) << 4);
                a[m] = *(const s16x8*)((const char*)ets + abyte);
            }
            s16x8 b = *(const s16x8*)(Woep + ((size_t)((kt * 128 + col) * 4 + kg)) * 8);
#pragma unroll
            for (int m = 0; m < 4; ++m) acc[m] = mfma16(a[m], b, acc[m]);
        }
        float bb = boe[col];
#pragma unroll
        for (int m = 0; m < 4; ++m)
#pragma unroll
            for (int i = 0; i < 4; ++i) {
                int rr = m * 16 + kg * 4 + i;
                int rbyte = (rr * 256 + col * 2) ^ ((rr & 7) << 4);
                float res = b2f(*(const unsigned short*)((const char*)eas + rbyte));
                size_t idx = (size_t)(e0 + rr) * 128 + col;
                float v = (res + acc[m][i] + bb) * BNS;
                if (IN_F32) eout_b[idx] = bf16r(v);
                else        eout_f[idx] = v;
            }
    }
}

// Node attention: one 64-lane wave per node. sc/e_t in CSR order -> coalesced;
// only the Vh gather (L2-resident) is random.
__global__ __launch_bounds__(64) void k_nattn(const int* __restrict__ offs, const int* __restrict__ csr_src,
                                              const float* __restrict__ sc,
                                              const unsigned short* __restrict__ e_t,
                                              const unsigned short* __restrict__ Vh,
                                              float* __restrict__ wV, float* __restrict__ rowV) {
    int n = blockIdx.x;
    int lane = threadIdx.x;
    int beg = offs[n], end = offs[n + 1];
    int h = lane & 7, es = lane >> 3;
    float m = -1e30f;
    for (int i = beg + es; i < end; i += 8)
        m = fmaxf(m, sc[(size_t)i * 8 + h]);
#pragma unroll
    for (int off = 8; off < 64; off <<= 1) m = fmaxf(m, __shfl_xor(m, off));
    float dsum = 0.0f;
    for (int i = beg + es; i < end; i += 8)
        dsum += expf(sc[(size_t)i * 8 + h] - m);
#pragma unroll
    for (int off = 8; off < 64; off <<= 1) dsum += __shfl_xor(dsum, off);
    float inv_d = 1.0f / (dsum + 1e-16f);

    int hv = lane >> 3;                    // head of cols (2*lane, 2*lane+1)
    float mv = __shfl(m, hv);
    float idv = __shfl(inv_d, hv);
    float av0 = 0.0f, av1 = 0.0f, ar0 = 0.0f, ar1 = 0.0f;
    for (int i = beg; i < end; ++i) {
        float a = expf(sc[(size_t)i * 8 + hv] - mv) * idv;
        int s = csr_src[i];
        int v = ((const int*)Vh)[(size_t)s * 64 + lane];
        int u = ((const int*)e_t)[(size_t)i * 64 + lane];
        av0 += b2f((unsigned short)v) * a;
        av1 += b2f((unsigned short)((unsigned)v >> 16)) * a;
        ar0 += b2f((unsigned short)u) * a;
        ar1 += b2f((unsigned short)((unsigned)u >> 16)) * a;
    }
    *(float2*)(wV + (size_t)n * 128 + 2 * lane)   = make_float2(av0, av1);
    *(float2*)(rowV + (size_t)n * 128 + 2 * lane) = make_float2(ar0, ar1);
}

// Node post via MFMA: 64 nodes/block, 512 threads (8 waves).
// p1: hs = (wV +[C-preload] rowV@VeRowBD) * degscale  ->  p2: h1 = (x + hs@Woh + boh)*BNS (f32 in regs)
// p3: us = relu(h1@W1 + b1)  ->  p4: out = (h1 + us@W2 + b2)*BNS
__global__ __launch_bounds__(512) void k_nodeB(const float* __restrict__ wV, const float* __restrict__ rowV,
                                               const short* __restrict__ VRp, const float* __restrict__ dc,
                                               const float* __restrict__ logdeg, const float* __restrict__ x,
                                               const short* __restrict__ Wohp, const float* __restrict__ boh,
                                               const short* __restrict__ W1p, const float* __restrict__ b1,
                                               const short* __restrict__ W2p, const float* __restrict__ b2,
                                               float* __restrict__ xout) {
    __shared__ short bufA[64 * 128];   // rowV staging, then h1 (16 KB)
    __shared__ short bufB[64 * 128];   // hs (16 KB)
    __shared__ short usw[64 * 256];    // us (32 KB)
    int n0 = blockIdx.x * 64;
    int t = threadIdx.x;
    int ci = t & 15, r0 = t >> 4;
    {   // p0: stage rowV -> bufA bf16 swizzled
#pragma unroll
        for (int h = 0; h < 2; ++h) {
            int rr = r0 + h * 32, n = n0 + rr;
            int4 pkv = make_int4(0, 0, 0, 0);
            if (n < NN) {
                const float4* src = (const float4*)(rowV + (size_t)n * 128 + ci * 8);
                float4 v0 = src[0], v1 = src[1];
                pkv.x = pk2(v0.x, v0.y); pkv.y = pk2(v0.z, v0.w);
                pkv.z = pk2(v1.x, v1.y); pkv.w = pk2(v1.z, v1.w);
            }
            int byte = (rr * 256 + ci * 16) ^ ((rr & 7) << 4);
            *(int4*)((char*)bufA + byte) = pkv;
        }
    }
    __syncthreads();
    int lane = t & 63, w = t >> 6;
    int l15 = lane & 15, kg = lane >> 4;
    int col = w * 16 + l15;
    {   // p1: hs
        f32x4 acc[4];
#pragma unroll
        for (int m = 0; m < 4; ++m)
#pragma unroll
            for (int i = 0; i < 4; ++i) {
                int n = n0 + m * 16 + kg * 4 + i;
                acc[m][i] = (n < NN) ? wV[(size_t)n * 128 + col] : 0.f;
            }
#pragma unroll
        for (int kt = 0; kt < 4; ++kt) {
            s16x8 a[4];
#pragma unroll
            for (int m = 0; m < 4; ++m) {
                int row = m * 16 + l15;
                int abyte = (row * 256 + kt * 64 + kg * 16) ^ ((l15 & 7) << 4);
                a[m] = *(const s16x8*)((const char*)bufA + abyte);
            }
            s16x8 b = *(const s16x8*)(VRp + ((size_t)((kt * 128 + col) * 4 + kg)) * 8);
#pragma unroll
            for (int m = 0; m < 4; ++m) acc[m] = mfma16(a[m], b, acc[m]);
        }
        float d0 = dc[col * 2], d1 = dc[col * 2 + 1];
#pragma unroll
        for (int m = 0; m < 4; ++m)
#pragma unroll
            for (int i = 0; i < 4; ++i) {
                int rr = m * 16 + kg * 4 + i, n = n0 + rr;
                float ld = (n < NN) ? logdeg[n] : 0.f;
                float hs = acc[m][i] * (d0 + ld * d1);
                int byte = (rr * 256 + col * 2) ^ ((rr & 7) << 4);
                *(unsigned short*)((char*)bufB + byte) = bf16r(hs);
            }
    }
    __syncthreads();
    float h1r[4][4];
    {   // p2: h1 (f32 regs + bf16 -> bufA)
        f32x4 acc[4];
#pragma unroll
        for (int m = 0; m < 4; ++m) { acc[m][0] = 0.f; acc[m][1] = 0.f; acc[m][2] = 0.f; acc[m][3] = 0.f; }
#pragma unroll
        for (int kt = 0; kt < 4; ++kt) {
            s16x8 a[4];
#pragma unroll
            for (int m = 0; m < 4; ++m) {
                int row = m * 16 + l15;
                int abyte = (row * 256 + kt * 64 + kg * 16) ^ ((l15 & 7) << 4);
                a[m] = *(const s16x8*)((const char*)bufB + abyte);
            }
            s16x8 b = *(const s16x8*)(Wohp + ((size_t)((kt * 128 + col) * 4 + kg)) * 8);
#pragma unroll
            for (int m = 0; m < 4; ++m) acc[m] = mfma16(a[m], b, acc[m]);
        }
        float bb = boh[col];
#pragma unroll
        for (int m = 0; m < 4; ++m)
#pragma unroll
            for (int i = 0; i < 4; ++i) {
                int rr = m * 16 + kg * 4 + i, n = n0 + rr;
                float xv = (n < NN) ? x[(size_t)n * 128 + col] : 0.f;
                float h1 = (xv + acc[m][i] + bb) * BNS;
                h1r[m][i] = h1;
                int byte = (rr * 256 + col * 2) ^ ((rr & 7) << 4);
                *(unsigned short*)((char*)bufA + byte) = bf16r(h1);
            }
    }
    __syncthreads();
    {   // p3: us = relu(h1@W1 + b1), 256 cols: wave w owns cols w*32..w*32+31
        f32x4 acc[4][2];
#pragma unroll
        for (int m = 0; m < 4; ++m)
#pragma unroll
            for (int q = 0; q < 2; ++q) { acc[m][q][0] = 0.f; acc[m][q][1] = 0.f; acc[m][q][2] = 0.f; acc[m][q][3] = 0.f; }
#pragma unroll
        for (int kt = 0; kt < 4; ++kt) {
            s16x8 a[4];
#pragma unroll
            for (int m = 0; m < 4; ++m) {
                int row = m * 16 + l15;
                int abyte = (row * 256 + kt * 64 + kg * 16) ^ ((l15 & 7) << 4);
                a[m] = *(const s16x8*)((const char*)bufA + abyte);
            }
#pragma unroll
            for (int q = 0; q < 2; ++q) {
                int colq = w * 32 + q * 16 + l15;
                s16x8 b = *(const s16x8*)(W1p + ((size_t)((kt * 256 + colq) * 4 + kg)) * 8);
#pragma unroll
                for (int m = 0; m < 4; ++m) acc[m][q] = mfma16(a[m], b, acc[m][q]);
            }
        }
#pragma unroll
        for (int q = 0; q < 2; ++q) {
            int colq = w * 32 + q * 16 + l15;
            float bb = b1[colq];
#pragma unroll
            for (int m = 0; m < 4; ++m)
#pragma unroll
                for (int i = 0; i < 4; ++i) {
                    int rr = m * 16 + kg * 4 + i;
                    float us = fmaxf(acc[m][q][i] + bb, 0.f);
                    int byte = (rr * 512 + colq * 2) ^ ((rr & 7) << 4);
                    *(unsigned short*)((char*)usw + byte) = bf16r(us);
                }
        }
    }
    __syncthreads();
    {   // p4: h2 = us@W2 + b2 (K=256, 8 kt); out = (h1 + h2)*BNS
        f32x4 acc[4];
#pragma unroll
        for (int m = 0; m < 4; ++m) { acc[m][0] = 0.f; acc[m][1] = 0.f; acc[m][2] = 0.f; acc[m][3] = 0.f; }
#pragma unroll
        for (int kt = 0; kt < 8; ++kt) {
            s16x8 a[4];
#pragma unroll
            for (int m = 0; m < 4; ++m) {
                int row = m * 16 + l15;
                int abyte = (row * 512 + kt * 64 + kg * 16) ^ ((l15 & 7) << 4);
                a[m] = *(const s16x8*)((const char*)usw + abyte);
            }
            s16x8 b = *(const s16x8*)(W2p + ((size_t)((kt * 128 + col) * 4 + kg)) * 8);
#pragma unroll
            for (int m = 0; m < 4; ++m) acc[m] = mfma16(a[m], b, acc[m]);
        }
        float bb = b2[col];
#pragma unroll
        for (int m = 0; m < 4; ++m)
#pragma unroll
            for (int i = 0; i < 4; ++i) {
                int n = n0 + m * 16 + kg * 4 + i;
                if (n < NN) xout[(size_t)n * 128 + col] = (h1r[m][i] + acc[m][i] + bb) * BNS;
            }
    }
}

// ---------------- host launch ----------------

extern "C" void kernel_launch(void* const* d_in, const int* in_sizes, int n_in,
                              void* d_out, int out_size, void* d_ws, size_t ws_size,
                              hipStream_t stream) {
    (void)in_sizes; (void)n_in; (void)out_size; (void)ws_size;
    const float* x_in0  = (const float*)d_in[0];
    const int*   ei     = (const int*)d_in[1];
    const float* ea_in0 = (const float*)d_in[2];
    const float* Wq = (const float*)d_in[3];
    const float* bq = (const float*)d_in[4];
    const float* Wk = (const float*)d_in[5];
    const float* Wv = (const float*)d_in[6];
    const float* We = (const float*)d_in[7];
    const float* be = (const float*)d_in[8];
    const float* Aw = (const float*)d_in[9];
    const float* VeRow = (const float*)d_in[10];
    const float* Woh = (const float*)d_in[11];
    const float* boh = (const float*)d_in[12];
    const float* Woe = (const float*)d_in[13];
    const float* boe = (const float*)d_in[14];
    const float* dc  = (const float*)d_in[15];
    const float* W1 = (const float*)d_in[16];
    const float* b1 = (const float*)d_in[17];
    const float* W2 = (const float*)d_in[18];
    const float* b2 = (const float*)d_in[19];

    char* ws = (char*)d_ws;
    size_t off = 0;
    auto alloc = [&](size_t bytes) { void* p = ws + off; off = (off + bytes + 255) & ~(size_t)255; return p; };
    int*   deg    = (int*)alloc((size_t)NN * 4);
    int*   cursor = (int*)alloc((size_t)NN * 4);
    int*   offs   = (int*)alloc((size_t)(NN + 1) * 4);
    int*   csr_src= (int*)alloc((size_t)NE * 4);
    int*   epos   = (int*)alloc((size_t)NE * 4);
    float* logdeg = (float*)alloc((size_t)NN * 4);
    unsigned short* Qh = (unsigned short*)alloc((size_t)NN * 128 * 2);
    unsigned short* Kh = (unsigned short*)alloc((size_t)NN * 128 * 2);
    unsigned short* Vh = (unsigned short*)alloc((size_t)NN * 128 * 2);
    unsigned short* e_t = (unsigned short*)alloc((size_t)NE * 128 * 2);
    unsigned short* ea_bf = (unsigned short*)alloc((size_t)NE * 128 * 2);
    float* sc     = (float*)alloc((size_t)NE * 8 * 4);
    float* wV     = (float*)alloc((size_t)NN * 128 * 4);
    float* rowV   = (float*)alloc((size_t)NN * 128 * 4);
    short* Wep    = (short*)alloc((size_t)2 * 128 * 256 * 2);
    short* Woep   = (short*)alloc((size_t)2 * 128 * 128 * 2);
    short* Wqp    = (short*)alloc((size_t)2 * 128 * 128 * 2);
    short* Wkp    = (short*)alloc((size_t)2 * 128 * 128 * 2);
    short* Wvp    = (short*)alloc((size_t)2 * 128 * 128 * 2);
    short* Wohp   = (short*)alloc((size_t)2 * 128 * 128 * 2);
    short* W1p    = (short*)alloc((size_t)2 * 128 * 256 * 2);
    short* W2p    = (short*)alloc((size_t)2 * 256 * 128 * 2);
    short* VRp    = (short*)alloc((size_t)2 * 128 * 128 * 2);

    float* out_x = (float*)d_out;
    float* out_e = out_x + (size_t)NN * 128;

    hipError_t err;
    err = hipMemsetAsync(deg, 0, (size_t)NN * 4, stream); (void)err;
    err = hipMemsetAsync(cursor, 0, (size_t)NN * 4, stream); (void)err;

    k_deg<<<(NE + 255) / 256, 256, 0, stream>>>(ei, deg);
    k_scan<<<1, 1024, 0, stream>>>(deg, offs);
    k_fill<<<(NE + 255) / 256, 256, 0, stream>>>(ei, offs, cursor, csr_src, epos);
    k_logdeg<<<(NN + 255) / 256, 256, 0, stream>>>(deg, logdeg);

    for (int l = 0; l < 2; ++l) {
        k_packW<<<128, 256, 0, stream>>>(We  + (size_t)l * 128 * 256, 256, 128 * 256, Wep  + (size_t)l * 128 * 256);
        k_packW<<<64,  256, 0, stream>>>(Woe + (size_t)l * 128 * 128, 128, 128 * 128, Woep + (size_t)l * 128 * 128);
        k_packW<<<64,  256, 0, stream>>>(Wq  + (size_t)l * 128 * 128, 128, 128 * 128, Wqp  + (size_t)l * 128 * 128);
        k_packW<<<64,  256, 0, stream>>>(Wk  + (size_t)l * 128 * 128, 128, 128 * 128, Wkp  + (size_t)l * 128 * 128);
        k_packW<<<64,  256, 0, stream>>>(Wv  + (size_t)l * 128 * 128, 128, 128 * 128, Wvp  + (size_t)l * 128 * 128);
        k_packW<<<64,  256, 0, stream>>>(Woh + (size_t)l * 128 * 128, 128, 128 * 128, Wohp + (size_t)l * 128 * 128);
        k_packW<<<128, 256, 0, stream>>>(W1  + (size_t)l * 128 * 256, 256, 128 * 256, W1p  + (size_t)l * 128 * 256);
        k_packW<<<128, 256, 0, stream>>>(W2  + (size_t)l * 256 * 128, 128, 256 * 128, W2p  + (size_t)l * 256 * 128);
        k_packVR<<<64, 256, 0, stream>>>(VeRow + (size_t)l * 16 * 128, VRp + (size_t)l * 128 * 128);
    }

    for (int l = 0; l < 2; ++l) {
        const float* x_l  = (l == 0) ? x_in0 : out_x;
        const short* Wqp_l = Wqp + (size_t)l * 128 * 128;
        const float* bq_l = bq + (size_t)l * 128;
        const short* Wkp_l = Wkp + (size_t)l * 128 * 128;
        const short* Wvp_l = Wvp + (size_t)l * 128 * 128;
        const short* Wep_l = Wep + (size_t)l * 128 * 256;
        const float* be_l = be + (size_t)l * 256;
        const float* Aw_l = Aw + (size_t)l * 16 * 8;
        const short* VRp_l = VRp + (size_t)l * 128 * 128;
        const short* Wohp_l = Wohp + (size_t)l * 128 * 128;
        const float* boh_l = boh + (size_t)l * 128;
        const short* Woep_l = Woep + (size_t)l * 128 * 128;
        const float* boe_l = boe + (size_t)l * 128;
        const float* dc_l  = dc + (size_t)l * 128 * 2;
        const short* W1p_l = W1p + (size_t)l * 128 * 256;
        const float* b1_l = b1 + (size_t)l * 256;
        const short* W2p_l = W2p + (size_t)l * 256 * 128;
        const float* b2_l = b2 + (size_t)l * 128;

        k_qkv<<<(NN + 63) / 64, 512, 0, stream>>>(x_l, Wqp_l, bq_l, Wkp_l, Wvp_l, Qh, Kh, Vh);
        if (l == 0) {
            k_edgeA<true><<<NE / 64, 512, 0, stream>>>(ea_in0, ei, epos, Wep_l, be_l, Aw_l, Qh, Kh,
                                                       e_t, sc, Woep_l, boe_l, ea_bf);
        } else {
            k_edgeA<false><<<NE / 64, 512, 0, stream>>>(ea_bf, ei, epos, Wep_l, be_l, Aw_l, Qh, Kh,
                                                        e_t, sc, Woep_l, boe_l, out_e);
        }
        k_nattn<<<NN, 64, 0, stream>>>(offs, csr_src, sc, e_t, Vh, wV, rowV);
        k_nodeB<<<(NN + 63) / 64, 512, 0, stream>>>(wV, rowV, VRp_l, dc_l, logdeg, x_l,
                                                    Wohp_l, boh_l, W1p_l, b1_l, W2p_l, b2_l, out_x);
    }
}

// Round 9
// 1046.360 us; speedup vs baseline: 2.2569x; 1.0867x over previous
//
#include <hip/hip_runtime.h>

#define NN 50000
#define NE 800000
#define CLAMPV 5.0f
#define BNS 0.9999950000374997f
#define EPKS 132   // int stride of packed Ep rows
#define NBLK 49    // ceil(NN/1024)

typedef __attribute__((ext_vector_type(8))) short s16x8;
typedef __attribute__((ext_vector_type(8))) __bf16 bf16x8;
typedef __attribute__((ext_vector_type(4))) float f32x4;

__device__ inline f32x4 mfma16(s16x8 a, s16x8 b, f32x4 c) {
    return __builtin_amdgcn_mfma_f32_16x16x32_bf16(
        __builtin_bit_cast(bf16x8, a), __builtin_bit_cast(bf16x8, b), c, 0, 0, 0);
}

__device__ inline unsigned short bf16r(float f) {
    return __builtin_bit_cast(unsigned short, (__bf16)f);
}

__device__ inline int pk2(float a, float b) {
    return (int)(unsigned)bf16r(a) | ((int)(unsigned)bf16r(b) << 16);
}

__device__ inline float b2f(unsigned short u) {
    return __builtin_bit_cast(float, (unsigned)u << 16);
}

// ---------------- degree / CSR build ----------------

__global__ __launch_bounds__(256) void k_deg(const int* __restrict__ ei, int* __restrict__ deg) {
    int e = blockIdx.x * 256 + threadIdx.x;
    if (e < NE) atomicAdd(&deg[ei[NE + e]], 1);
}

// hierarchical scan: local inclusive scans + block sums
__global__ __launch_bounds__(1024) void k_scan1(const int* __restrict__ deg, int* __restrict__ offs,
                                                int* __restrict__ bsum) {
    __shared__ int sm[1024];
    int i = blockIdx.x * 1024 + threadIdx.x;
    int v = (i < NN) ? deg[i] : 0;
    sm[threadIdx.x] = v;
    __syncthreads();
    for (int s = 1; s < 1024; s <<= 1) {
        int t = (threadIdx.x >= s) ? sm[threadIdx.x - s] : 0;
        __syncthreads();
        sm[threadIdx.x] += t;
        __syncthreads();
    }
    if (i < NN) offs[i + 1] = sm[threadIdx.x];
    if (threadIdx.x == 1023) bsum[blockIdx.x] = sm[1023];
    if (blockIdx.x == 0 && threadIdx.x == 0) offs[0] = 0;
}

__global__ void k_scan2(int* __restrict__ bsum) {
    if (threadIdx.x == 0) {
        int acc = 0;
        for (int i = 0; i < NBLK; ++i) { int v = bsum[i]; bsum[i] = acc; acc += v; }
    }
}

__global__ __launch_bounds__(1024) void k_scan3(int* __restrict__ offs, const int* __restrict__ bsum) {
    int i = blockIdx.x * 1024 + threadIdx.x;
    if (i < NN) offs[i + 1] += bsum[blockIdx.x];
}

// csr_src[pos] = src node of the edge in CSR slot pos; epos[e] = CSR slot of edge e.
__global__ __launch_bounds__(256) void k_fill(const int* __restrict__ ei, const int* __restrict__ offs,
                                              int* __restrict__ cursor, int* __restrict__ csr_src,
                                              int* __restrict__ epos) {
    int e = blockIdx.x * 256 + threadIdx.x;
    if (e < NE) {
        int d = ei[NE + e];
        int pos = offs[d] + atomicAdd(&cursor[d], 1);
        csr_src[pos] = ei[e];
        epos[e] = pos;
    }
}

__global__ __launch_bounds__(256) void k_logdeg(const int* __restrict__ deg, float* __restrict__ logdeg) {
    int i = blockIdx.x * 256 + threadIdx.x;
    if (i < NN) logdeg[i] = logf((float)deg[i] + 1.0f);
}

// One launch packs ALL weights (both layers) into MFMA B-fragment order.
// Within-layer pack index q = ((kt*ncol + col)*4 + kg)*8 + j ; k = kt*32 + kg*8 + j.
#define PL_A (128*256)
#define PL_B (128*128)
__global__ __launch_bounds__(256) void k_packAll(
    const float* __restrict__ We,  const float* __restrict__ Woe, const float* __restrict__ Wq,
    const float* __restrict__ Wk,  const float* __restrict__ Wv,  const float* __restrict__ Woh,
    const float* __restrict__ W1,  const float* __restrict__ W2,  const float* __restrict__ VR,
    short* __restrict__ Wep,  short* __restrict__ Woep, short* __restrict__ Wqp,
    short* __restrict__ Wkp,  short* __restrict__ Wvp,  short* __restrict__ Wohp,
    short* __restrict__ W1p,  short* __restrict__ W2p,  short* __restrict__ VRp) {
    int s = blockIdx.x * 256 + threadIdx.x;
    const float* W; short* out; int ncol, perL; bool vr = false;
    if (s < 2 * PL_A) { W = We; out = Wep; ncol = 256; perL = PL_A; }
    else if ((s -= 2 * PL_A) < 2 * PL_B) { W = Woe; out = Woep; ncol = 128; perL = PL_B; }
    else if ((s -= 2 * PL_B) < 2 * PL_B) { W = Wq;  out = Wqp;  ncol = 128; perL = PL_B; }
    else if ((s -= 2 * PL_B) < 2 * PL_B) { W = Wk;  out = Wkp;  ncol = 128; perL = PL_B; }
    else if ((s -= 2 * PL_B) < 2 * PL_B) { W = Wv;  out = Wvp;  ncol = 128; perL = PL_B; }
    else if ((s -= 2 * PL_B) < 2 * PL_B) { W = Woh; out = Wohp; ncol = 128; perL = PL_B; }
    else if ((s -= 2 * PL_B) < 2 * PL_A) { W = W1;  out = W1p;  ncol = 256; perL = PL_A; }
    else if ((s -= 2 * PL_A) < 2 * PL_A) { W = W2;  out = W2p;  ncol = 128; perL = PL_A; }  // K=256
    else if ((s -= 2 * PL_A) < 2 * PL_B) { W = VR;  out = VRp;  ncol = 128; perL = PL_B; vr = true; }
    else return;
    int l = s / perL, q = s % perL;
    int j = q & 7; int t2 = q >> 3; int kg = t2 & 3; t2 >>= 2;
    int col = t2 % ncol; int kt = t2 / ncol;
    int k = kt * 32 + kg * 8 + j;
    float v;
    if (vr) v = ((k >> 4) == (col >> 4)) ? VR[l * 2048 + (k & 15) * 128 + col] : 0.f;
    else    v = W[(size_t)l * perL + k * ncol + col];
    out[(size_t)l * perL + q] = (short)bf16r(v);
}

// ---------------- per-layer kernels ----------------

// Q/K/V via MFMA: 64 nodes/block, 512 threads (8 waves).
__global__ __launch_bounds__(512) void k_qkv(const float* __restrict__ x,
                                             const short* __restrict__ Wqp, const float* __restrict__ bq,
                                             const short* __restrict__ Wkp, const short* __restrict__ Wvp,
                                             unsigned short* __restrict__ Qh, unsigned short* __restrict__ Kh,
                                             unsigned short* __restrict__ Vh) {
    __shared__ short xsw[64 * 128];   // bf16, XOR-swizzled
    int t = threadIdx.x;
    int ci = t & 15, r0 = t >> 4;     // r0 in 0..31
    int n0 = blockIdx.x * 64;
    for (int rr = r0; rr < 64; rr += 32) {
        int n = n0 + rr;
        int4 pkv = make_int4(0, 0, 0, 0);
        if (n < NN) {
            const float4* src = (const float4*)(x + (size_t)n * 128 + ci * 8);
            float4 v0 = src[0], v1 = src[1];
            pkv.x = pk2(v0.x, v0.y); pkv.y = pk2(v0.z, v0.w);
            pkv.z = pk2(v1.x, v1.y); pkv.w = pk2(v1.z, v1.w);
        }
        int byte = (rr * 256 + ci * 16) ^ ((rr & 7) << 4);
        *(int4*)((char*)xsw + byte) = pkv;
    }
    __syncthreads();
    int lane = t & 63, w = t >> 6;
    int l15 = lane & 15, kg = lane >> 4;
    f32x4 acc[4][3];
#pragma unroll
    for (int m = 0; m < 4; ++m)
#pragma unroll
        for (int q = 0; q < 3; ++q) { acc[m][q][0] = 0.f; acc[m][q][1] = 0.f; acc[m][q][2] = 0.f; acc[m][q][3] = 0.f; }
    int col = w * 16 + l15;
#pragma unroll
    for (int kt = 0; kt < 4; ++kt) {
        s16x8 a[4];
#pragma unroll
        for (int m = 0; m < 4; ++m) {
            int row = m * 16 + l15;
            int abyte = (row * 256 + kt * 64 + kg * 16) ^ ((l15 & 7) << 4);
            a[m] = *(const s16x8*)((const char*)xsw + abyte);
        }
        size_t bo = ((size_t)((kt * 128 + col) * 4 + kg)) * 8;
        s16x8 bqf = *(const s16x8*)(Wqp + bo);
        s16x8 bkf = *(const s16x8*)(Wkp + bo);
        s16x8 bvf = *(const s16x8*)(Wvp + bo);
#pragma unroll
        for (int m = 0; m < 4; ++m) {
            acc[m][0] = mfma16(a[m], bqf, acc[m][0]);
            acc[m][1] = mfma16(a[m], bkf, acc[m][1]);
            acc[m][2] = mfma16(a[m], bvf, acc[m][2]);
        }
    }
    float bqv = bq[col];
#pragma unroll
    for (int m = 0; m < 4; ++m)
#pragma unroll
        for (int i = 0; i < 4; ++i) {
            int n = n0 + m * 16 + kg * 4 + i;
            if (n < NN) {
                Qh[(size_t)n * 128 + col] = bf16r(acc[m][0][i] + bqv);
                Kh[(size_t)n * 128 + col] = bf16r(acc[m][1][i]);
                Vh[(size_t)n * 128 + col] = bf16r(acc[m][2][i]);
            }
        }
}

// Fused edge kernel: 64 edges/block, 512 threads (8 waves). epk and ets share one LDS buffer
// (phase 3 reads epk to regs, barrier, writes ets into same region) -> 49 KB -> 3 blocks/CU.
template<bool IN_F32>
__global__ __launch_bounds__(512) void k_edgeA(const void* __restrict__ ea_, const int* __restrict__ ei,
                                               const int* __restrict__ epos,
                                               const short* __restrict__ Wep, const float* __restrict__ be,
                                               const float* __restrict__ Aw,
                                               const unsigned short* __restrict__ Qh,
                                               const unsigned short* __restrict__ Kh,
                                               unsigned short* __restrict__ e_t, float* __restrict__ sc,
                                               const short* __restrict__ Woep, const float* __restrict__ boe,
                                               void* __restrict__ eout_) {
    __shared__ short eas[64 * 128];          // bf16 ea tile, XOR-swizzled (16 KB)
    __shared__ int epts[64 * EPKS];          // union: epk pairs, then ets bf16 tile (33.8 KB)
    const float* eaf = (const float*)ea_;
    const unsigned short* eab = (const unsigned short*)ea_;
    unsigned short* eout_b = (unsigned short*)eout_;
    float* eout_f = (float*)eout_;

    int e0 = blockIdx.x * 64;
    int t = threadIdx.x;
    int ci = t & 15, r0 = t >> 4;            // r0 in 0..31; thread owns edges r0 and r0+32
    int eA = e0 + r0, eB = eA + 32;
    int siA = ei[eA], diA = ei[NE + eA], posA = epos[eA];
    int siB = ei[eB], diB = ei[NE + eB], posB = epos[eB];

    {   // phase 1: stage ea -> bf16 swizzled (2 rows/thread)
#pragma unroll
        for (int h = 0; h < 2; ++h) {
            int rr = r0 + h * 32;
            int4 pkv;
            if (IN_F32) {
                const float4* src = (const float4*)(eaf + (size_t)(e0 + rr) * 128 + ci * 8);
                float4 v0 = src[0], v1 = src[1];
                pkv.x = pk2(v0.x, v0.y); pkv.y = pk2(v0.z, v0.w);
                pkv.z = pk2(v1.x, v1.y); pkv.w = pk2(v1.z, v1.w);
            } else {
                pkv = *(const int4*)(eab + (size_t)(e0 + rr) * 128 + ci * 8);
            }
            int byte = (rr * 256 + ci * 16) ^ ((rr & 7) << 4);
            *(int4*)((char*)eas + byte) = pkv;
        }
    }
    __syncthreads();
    // T14: issue K/Q gathers now — they fly under the whole phase-2 MFMA block
    union { int4 v; unsigned short us[8]; } kuA, quA, kuB, quB;
    kuA.v = *(const int4*)(Kh + (size_t)siA * 128 + ci * 8);
    quA.v = *(const int4*)(Qh + (size_t)diA * 128 + ci * 8);
    kuB.v = *(const int4*)(Kh + (size_t)siB * 128 + ci * 8);
    quB.v = *(const int4*)(Qh + (size_t)diB * 128 + ci * 8);

    int lane = t & 63, w = t >> 6;
    int l15 = lane & 15, kg = lane >> 4;
    {   // phase 2: Ep = eas(64x128) @ We(128x256) + be. Wave w owns head w's 32 cols.
        f32x4 acc[4][2];
#pragma unroll
        for (int m = 0; m < 4; ++m)
#pragma unroll
            for (int q = 0; q < 2; ++q) { acc[m][q][0] = 0.f; acc[m][q][1] = 0.f; acc[m][q][2] = 0.f; acc[m][q][3] = 0.f; }
#pragma unroll
        for (int kt = 0; kt < 4; ++kt) {
            s16x8 a[4];
#pragma unroll
            for (int m = 0; m < 4; ++m) {
                int row = m * 16 + l15;
                int abyte = (row * 256 + kt * 64 + kg * 16) ^ ((l15 & 7) << 4);
                a[m] = *(const s16x8*)((const char*)eas + abyte);
            }
#pragma unroll
            for (int q = 0; q < 2; ++q) {
                int col = w * 32 + q * 16 + l15;
                s16x8 b = *(const s16x8*)(Wep + ((size_t)((kt * 256 + col) * 4 + kg)) * 8);
#pragma unroll
                for (int m = 0; m < 4; ++m) acc[m][q] = mfma16(a[m], b, acc[m][q]);
            }
        }
        float bw = be[w * 32 + l15], bb = be[w * 32 + 16 + l15];
#pragma unroll
        for (int m = 0; m < 4; ++m)
#pragma unroll
            for (int i = 0; i < 4; ++i) {
                int row = m * 16 + kg * 4 + i;
                epts[row * EPKS + w * 16 + l15] = pk2(acc[m][0][i] + bw, acc[m][1][i] + bb);
            }
    }
    __syncthreads();
    // phase 3a: pull this thread's epk slices into registers
    int4 wA0, wA1, wB0, wB1;
    {
        const int4* pA = (const int4*)(epts + r0 * EPKS + ci * 8);
        wA0 = pA[0]; wA1 = pA[1];
        const int4* pB = (const int4*)(epts + (r0 + 32) * EPKS + ci * 8);
        wB0 = pB[0]; wB1 = pB[1];
    }
    __syncthreads();   // all epk reads done before ets overwrites the buffer
    {   // phase 3b: elementwise; write ets into union buffer + scatter e_t/sc to CSR slots
        int hh = ci >> 1, dbase = (ci & 1) * 8;
        float aw[8];
#pragma unroll
        for (int j = 0; j < 8; ++j) aw[j] = Aw[(dbase + j) * 8 + hh];
#pragma unroll
        for (int h = 0; h < 2; ++h) {
            int r = r0 + h * 32;
            int pos = h ? posB : posA;
            const unsigned short* kus = h ? kuB.us : kuA.us;
            const unsigned short* qus = h ? quB.us : quA.us;
            const int4 w0 = h ? wB0 : wA0;
            const int4 w1 = h ? wB1 : wA1;
            int prs[8] = {w0.x, w0.y, w0.z, w0.w, w1.x, w1.y, w1.z, w1.w};
            float p = 0.f;
            float etv[8];
#pragma unroll
            for (int j = 0; j < 8; ++j) {
                int pr = prs[j];
                float ew = b2f((unsigned short)pr);
                float ebv = b2f((unsigned short)((unsigned)pr >> 16));
                float kq = b2f(kus[j]) + b2f(qus[j]);
                float sv = kq * ew;
                float ss = copysignf(sqrtf(fabsf(sv)), sv);
                float et = fmaxf(ss + ebv, 0.f);
                etv[j] = et;
                p += et * aw[j];
            }
            int4 pkv;
            pkv.x = pk2(etv[0], etv[1]); pkv.y = pk2(etv[2], etv[3]);
            pkv.z = pk2(etv[4], etv[5]); pkv.w = pk2(etv[6], etv[7]);
            *(int4*)(e_t + (size_t)pos * 128 + ci * 8) = pkv;
            int byte = (r * 256 + ci * 16) ^ ((r & 7) << 4);
            *(int4*)((char*)epts + byte) = pkv;
            p += __shfl_xor(p, 1);
            if ((ci & 1) == 0) {
                float s = fminf(fmaxf(p, -CLAMPV), CLAMPV);
                sc[(size_t)pos * 8 + hh] = s;
            }
        }
    }
    __syncthreads();
    {   // phase 4: e_out = (ea + ets(64x128) @ Woe(128x128) + boe) * BNS. Wave w owns col-tile w.
        f32x4 acc[4];
#pragma unroll
        for (int m = 0; m < 4; ++m) { acc[m][0] = 0.f; acc[m][1] = 0.f; acc[m][2] = 0.f; acc[m][3] = 0.f; }
        int col = w * 16 + l15;
#pragma unroll
        for (int kt = 0; kt < 4; ++kt) {
            s16x8 a[4];
#pragma unroll
            for (int m = 0; m < 4; ++m) {
                int row = m * 16 + l15;
                int abyte = (row * 256 + kt * 64 + kg * 16) ^ ((l15 & 7) << 4);
                a[m] = *(const s16x8*)((const char*)epts + abyte);
            }
            s16x8 b = *(const s16x8*)(Woep + ((size_t)((kt * 128 + col) * 4 + kg)) * 8);
#pragma unroll
            for (int m = 0; m < 4; ++m) acc[m] = mfma16(a[m], b, acc[m]);
        }
        float bb = boe[col];
#pragma unroll
        for (int m = 0; m < 4; ++m)
#pragma unroll
            for (int i = 0; i < 4; ++i) {
                int rr = m * 16 + kg * 4 + i;
                int rbyte = (rr * 256 + col * 2) ^ ((rr & 7) << 4);
                float res = b2f(*(const unsigned short*)((const char*)eas + rbyte));
                size_t idx = (size_t)(e0 + rr) * 128 + col;
                float v = (res + acc[m][i] + bb) * BNS;
                if (IN_F32) eout_b[idx] = bf16r(v);
                else        eout_f[idx] = v;
            }
    }
}

// Node attention: one 64-lane wave per node. sc/e_t in CSR order -> coalesced.
__global__ __launch_bounds__(64) void k_nattn(const int* __restrict__ offs, const int* __restrict__ csr_src,
                                              const float* __restrict__ sc,
                                              const unsigned short* __restrict__ e_t,
                                              const unsigned short* __restrict__ Vh,
                                              float* __restrict__ wV, float* __restrict__ rowV) {
    int n = blockIdx.x;
    int lane = threadIdx.x;
    int beg = offs[n], end = offs[n + 1];
    int h = lane & 7, es = lane >> 3;
    float m = -1e30f;
    for (int i = beg + es; i < end; i += 8)
        m = fmaxf(m, sc[(size_t)i * 8 + h]);
#pragma unroll
    for (int off = 8; off < 64; off <<= 1) m = fmaxf(m, __shfl_xor(m, off));
    float dsum = 0.0f;
    for (int i = beg + es; i < end; i += 8)
        dsum += expf(sc[(size_t)i * 8 + h] - m);
#pragma unroll
    for (int off = 8; off < 64; off <<= 1) dsum += __shfl_xor(dsum, off);
    float inv_d = 1.0f / (dsum + 1e-16f);

    int hv = lane >> 3;
    float mv = __shfl(m, hv);
    float idv = __shfl(inv_d, hv);
    float av0 = 0.0f, av1 = 0.0f, ar0 = 0.0f, ar1 = 0.0f;
    for (int i = beg; i < end; ++i) {
        float a = expf(sc[(size_t)i * 8 + hv] - mv) * idv;
        int s = csr_src[i];
        int v = ((const int*)Vh)[(size_t)s * 64 + lane];
        int u = ((const int*)e_t)[(size_t)i * 64 + lane];
        av0 += b2f((unsigned short)v) * a;
        av1 += b2f((unsigned short)((unsigned)v >> 16)) * a;
        ar0 += b2f((unsigned short)u) * a;
        ar1 += b2f((unsigned short)((unsigned)u >> 16)) * a;
    }
    *(float2*)(wV + (size_t)n * 128 + 2 * lane)   = make_float2(av0, av1);
    *(float2*)(rowV + (size_t)n * 128 + 2 * lane) = make_float2(ar0, ar1);
}

// Node post via MFMA: 64 nodes/block, 512 threads. hs shares LDS with us (48 KB -> 3 blocks/CU).
__global__ __launch_bounds__(512) void k_nodeB(const float* __restrict__ wV, const float* __restrict__ rowV,
                                               const short* __restrict__ VRp, const float* __restrict__ dc,
                                               const float* __restrict__ logdeg, const float* __restrict__ x,
                                               const short* __restrict__ Wohp, const float* __restrict__ boh,
                                               const short* __restrict__ W1p, const float* __restrict__ b1,
                                               const short* __restrict__ W2p, const float* __restrict__ b2,
                                               float* __restrict__ xout) {
    __shared__ short bufA[64 * 128];   // rowV staging, then h1 (16 KB)
    __shared__ short bufU[64 * 256];   // hs (first half layout), then us (32 KB)
    int n0 = blockIdx.x * 64;
    int t = threadIdx.x;
    int ci = t & 15, r0 = t >> 4;
    {   // p0: stage rowV -> bufA bf16 swizzled
#pragma unroll
        for (int h = 0; h < 2; ++h) {
            int rr = r0 + h * 32, n = n0 + rr;
            int4 pkv = make_int4(0, 0, 0, 0);
            if (n < NN) {
                const float4* src = (const float4*)(rowV + (size_t)n * 128 + ci * 8);
                float4 v0 = src[0], v1 = src[1];
                pkv.x = pk2(v0.x, v0.y); pkv.y = pk2(v0.z, v0.w);
                pkv.z = pk2(v1.x, v1.y); pkv.w = pk2(v1.z, v1.w);
            }
            int byte = (rr * 256 + ci * 16) ^ ((rr & 7) << 4);
            *(int4*)((char*)bufA + byte) = pkv;
        }
    }
    __syncthreads();
    int lane = t & 63, w = t >> 6;
    int l15 = lane & 15, kg = lane >> 4;
    int col = w * 16 + l15;
    {   // p1: hs = (wV + rowV@VeRowBD) * degscale -> bufU (hs layout)
        f32x4 acc[4];
#pragma unroll
        for (int m = 0; m < 4; ++m)
#pragma unroll
            for (int i = 0; i < 4; ++i) {
                int n = n0 + m * 16 + kg * 4 + i;
                acc[m][i] = (n < NN) ? wV[(size_t)n * 128 + col] : 0.f;
            }
#pragma unroll
        for (int kt = 0; kt < 4; ++kt) {
            s16x8 a[4];
#pragma unroll
            for (int m = 0; m < 4; ++m) {
                int row = m * 16 + l15;
                int abyte = (row * 256 + kt * 64 + kg * 16) ^ ((l15 & 7) << 4);
                a[m] = *(const s16x8*)((const char*)bufA + abyte);
            }
            s16x8 b = *(const s16x8*)(VRp + ((size_t)((kt * 128 + col) * 4 + kg)) * 8);
#pragma unroll
            for (int m = 0; m < 4; ++m) acc[m] = mfma16(a[m], b, acc[m]);
        }
        float d0 = dc[col * 2], d1 = dc[col * 2 + 1];
#pragma unroll
        for (int m = 0; m < 4; ++m)
#pragma unroll
            for (int i = 0; i < 4; ++i) {
                int rr = m * 16 + kg * 4 + i, n = n0 + rr;
                float ld = (n < NN) ? logdeg[n] : 0.f;
                float hs = acc[m][i] * (d0 + ld * d1);
                int byte = (rr * 256 + col * 2) ^ ((rr & 7) << 4);
                *(unsigned short*)((char*)bufU + byte) = bf16r(hs);
            }
    }
    __syncthreads();
    float h1r[4][4];
    {   // p2: h1 = (x + hs@Woh + boh)*BNS (f32 regs + bf16 -> bufA)
        f32x4 acc[4];
#pragma unroll
        for (int m = 0; m < 4; ++m) { acc[m][0] = 0.f; acc[m][1] = 0.f; acc[m][2] = 0.f; acc[m][3] = 0.f; }
#pragma unroll
        for (int kt = 0; kt < 4; ++kt) {
            s16x8 a[4];
#pragma unroll
            for (int m = 0; m < 4; ++m) {
                int row = m * 16 + l15;
                int abyte = (row * 256 + kt * 64 + kg * 16) ^ ((l15 & 7) << 4);
                a[m] = *(const s16x8*)((const char*)bufU + abyte);
            }
            s16x8 b = *(const s16x8*)(Wohp + ((size_t)((kt * 128 + col) * 4 + kg)) * 8);
#pragma unroll
            for (int m = 0; m < 4; ++m) acc[m] = mfma16(a[m], b, acc[m]);
        }
        float bb = boh[col];
#pragma unroll
        for (int m = 0; m < 4; ++m)
#pragma unroll
            for (int i = 0; i < 4; ++i) {
                int rr = m * 16 + kg * 4 + i, n = n0 + rr;
                float xv = (n < NN) ? x[(size_t)n * 128 + col] : 0.f;
                float h1 = (xv + acc[m][i] + bb) * BNS;
                h1r[m][i] = h1;
                int byte = (rr * 256 + col * 2) ^ ((rr & 7) << 4);
                *(unsigned short*)((char*)bufA + byte) = bf16r(h1);
            }
    }
    __syncthreads();
    {   // p3: us = relu(h1@W1 + b1) -> bufU (us layout; hs dead past p2, barrier-separated)
        f32x4 acc[4][2];
#pragma unroll
        for (int m = 0; m < 4; ++m)
#pragma unroll
            for (int q = 0; q < 2; ++q) { acc[m][q][0] = 0.f; acc[m][q][1] = 0.f; acc[m][q][2] = 0.f; acc[m][q][3] = 0.f; }
#pragma unroll
        for (int kt = 0; kt < 4; ++kt) {
            s16x8 a[4];
#pragma unroll
            for (int m = 0; m < 4; ++m) {
                int row = m * 16 + l15;
                int abyte = (row * 256 + kt * 64 + kg * 16) ^ ((l15 & 7) << 4);
                a[m] = *(const s16x8*)((const char*)bufA + abyte);
            }
#pragma unroll
            for (int q = 0; q < 2; ++q) {
                int colq = w * 32 + q * 16 + l15;
                s16x8 b = *(const s16x8*)(W1p + ((size_t)((kt * 256 + colq) * 4 + kg)) * 8);
#pragma unroll
                for (int m = 0; m < 4; ++m) acc[m][q] = mfma16(a[m], b, acc[m][q]);
            }
        }
        __syncthreads();   // hs reads (p2) complete before us overwrites bufU
#pragma unroll
        for (int q = 0; q < 2; ++q) {
            int colq = w * 32 + q * 16 + l15;
            float bb = b1[colq];
#pragma unroll
            for (int m = 0; m < 4; ++m)
#pragma unroll
                for (int i = 0; i < 4; ++i) {
                    int rr = m * 16 + kg * 4 + i;
                    float us = fmaxf(acc[m][q][i] + bb, 0.f);
                    int byte = (rr * 512 + colq * 2) ^ ((rr & 7) << 4);
                    *(unsigned short*)((char*)bufU + byte) = bf16r(us);
                }
        }
    }
    __syncthreads();
    {   // p4: h2 = us@W2 + b2 (K=256, 8 kt); out = (h1 + h2)*BNS
        f32x4 acc[4];
#pragma unroll
        for (int m = 0; m < 4; ++m) { acc[m][0] = 0.f; acc[m][1] = 0.f; acc[m][2] = 0.f; acc[m][3] = 0.f; }
#pragma unroll
        for (int kt = 0; kt < 8; ++kt) {
            s16x8 a[4];
#pragma unroll
            for (int m = 0; m < 4; ++m) {
                int row = m * 16 + l15;
                int abyte = (row * 512 + kt * 64 + kg * 16) ^ ((l15 & 7) << 4);
                a[m] = *(const s16x8*)((const char*)bufU + abyte);
            }
            s16x8 b = *(const s16x8*)(W2p + ((size_t)((kt * 128 + col) * 4 + kg)) * 8);
#pragma unroll
            for (int m = 0; m < 4; ++m) acc[m] = mfma16(a[m], b, acc[m]);
        }
        float bb = b2[col];
#pragma unroll
        for (int m = 0; m < 4; ++m)
#pragma unroll
            for (int i = 0; i < 4; ++i) {
                int n = n0 + m * 16 + kg * 4 + i;
                if (n < NN) xout[(size_t)n * 128 + col] = (h1r[m][i] + acc[m][i] + bb) * BNS;
            }
    }
}

// ---------------- host launch ----------------

extern "C" void kernel_launch(void* const* d_in, const int* in_sizes, int n_in,
                              void* d_out, int out_size, void* d_ws, size_t ws_size,
                              hipStream_t stream) {
    (void)in_sizes; (void)n_in; (void)out_size; (void)ws_size;
    const float* x_in0  = (const float*)d_in[0];
    const int*   ei     = (const int*)d_in[1];
    const float* ea_in0 = (const float*)d_in[2];
    const float* Wq = (const float*)d_in[3];
    const float* bq = (const float*)d_in[4];
    const float* Wk = (const float*)d_in[5];
    const float* Wv = (const float*)d_in[6];
    const float* We = (const float*)d_in[7];
    const float* be = (const float*)d_in[8];
    const float* Aw = (const float*)d_in[9];
    const float* VeRow = (const float*)d_in[10];
    const float* Woh = (const float*)d_in[11];
    const float* boh = (const float*)d_in[12];
    const float* Woe = (const float*)d_in[13];
    const float* boe = (const float*)d_in[14];
    const float* dc  = (const float*)d_in[15];
    const float* W1 = (const float*)d_in[16];
    const float* b1 = (const float*)d_in[17];
    const float* W2 = (const float*)d_in[18];
    const float* b2 = (const float*)d_in[19];

    char* ws = (char*)d_ws;
    size_t off = 0;
    auto alloc = [&](size_t bytes) { void* p = ws + off; off = (off + bytes + 255) & ~(size_t)255; return p; };
    int*   deg    = (int*)alloc((size_t)NN * 4);
    int*   cursor = (int*)alloc((size_t)NN * 4);
    int*   offs   = (int*)alloc((size_t)(NN + 1) * 4);
    int*   bsum   = (int*)alloc((size_t)64 * 4);
    int*   csr_src= (int*)alloc((size_t)NE * 4);
    int*   epos   = (int*)alloc((size_t)NE * 4);
    float* logdeg = (float*)alloc((size_t)NN * 4);
    unsigned short* Qh = (unsigned short*)alloc((size_t)NN * 128 * 2);
    unsigned short* Kh = (unsigned short*)alloc((size_t)NN * 128 * 2);
    unsigned short* Vh = (unsigned short*)alloc((size_t)NN * 128 * 2);
    unsigned short* e_t = (unsigned short*)alloc((size_t)NE * 128 * 2);
    unsigned short* ea_bf = (unsigned short*)alloc((size_t)NE * 128 * 2);
    float* sc     = (float*)alloc((size_t)NE * 8 * 4);
    float* wV     = (float*)alloc((size_t)NN * 128 * 4);
    float* rowV   = (float*)alloc((size_t)NN * 128 * 4);
    short* Wep    = (short*)alloc((size_t)2 * 128 * 256 * 2);
    short* Woep   = (short*)alloc((size_t)2 * 128 * 128 * 2);
    short* Wqp    = (short*)alloc((size_t)2 * 128 * 128 * 2);
    short* Wkp    = (short*)alloc((size_t)2 * 128 * 128 * 2);
    short* Wvp    = (short*)alloc((size_t)2 * 128 * 128 * 2);
    short* Wohp   = (short*)alloc((size_t)2 * 128 * 128 * 2);
    short* W1p    = (short*)alloc((size_t)2 * 128 * 256 * 2);
    short* W2p    = (short*)alloc((size_t)2 * 256 * 128 * 2);
    short* VRp    = (short*)alloc((size_t)2 * 128 * 128 * 2);

    float* out_x = (float*)d_out;
    float* out_e = out_x + (size_t)NN * 128;

    hipError_t err;
    err = hipMemsetAsync(deg, 0, (size_t)NN * 4, stream); (void)err;
    err = hipMemsetAsync(cursor, 0, (size_t)NN * 4, stream); (void)err;

    k_deg<<<(NE + 255) / 256, 256, 0, stream>>>(ei, deg);
    k_scan1<<<NBLK, 1024, 0, stream>>>(deg, offs, bsum);
    k_scan2<<<1, 64, 0, stream>>>(bsum);
    k_scan3<<<NBLK, 1024, 0, stream>>>(offs, bsum);
    k_fill<<<(NE + 255) / 256, 256, 0, stream>>>(ei, offs, cursor, csr_src, epos);
    k_logdeg<<<(NN + 255) / 256, 256, 0, stream>>>(deg, logdeg);
    k_packAll<<<1536, 256, 0, stream>>>(We, Woe, Wq, Wk, Wv, Woh, W1, W2, VeRow,
                                        Wep, Woep, Wqp, Wkp, Wvp, Wohp, W1p, W2p, VRp);

    for (int l = 0; l < 2; ++l) {
        const float* x_l  = (l == 0) ? x_in0 : out_x;
        const short* Wqp_l = Wqp + (size_t)l * 128 * 128;
        const float* bq_l = bq + (size_t)l * 128;
        const short* Wkp_l = Wkp + (size_t)l * 128 * 128;
        const short* Wvp_l = Wvp + (size_t)l * 128 * 128;
        const short* Wep_l = Wep + (size_t)l * 128 * 256;
        const float* be_l = be + (size_t)l * 256;
        const float* Aw_l = Aw + (size_t)l * 16 * 8;
        const short* VRp_l = VRp + (size_t)l * 128 * 128;
        const short* Wohp_l = Wohp + (size_t)l * 128 * 128;
        const float* boh_l = boh + (size_t)l * 128;
        const short* Woep_l = Woep + (size_t)l * 128 * 128;
        const float* boe_l = boe + (size_t)l * 128;
        const float* dc_l  = dc + (size_t)l * 128 * 2;
        const short* W1p_l = W1p + (size_t)l * 128 * 256;
        const float* b1_l = b1 + (size_t)l * 256;
        const short* W2p_l = W2p + (size_t)l * 256 * 128;
        const float* b2_l = b2 + (size_t)l * 128;

        k_qkv<<<(NN + 63) / 64, 512, 0, stream>>>(x_l, Wqp_l, bq_l, Wkp_l, Wvp_l, Qh, Kh, Vh);
        if (l == 0) {
            k_edgeA<true><<<NE / 64, 512, 0, stream>>>(ea_in0, ei, epos, Wep_l, be_l, Aw_l, Qh, Kh,
                                                       e_t, sc, Woep_l, boe_l, ea_bf);
        } else {
            k_edgeA<false><<<NE / 64, 512, 0, stream>>>(ea_bf, ei, epos, Wep_l, be_l, Aw_l, Qh, Kh,
                                                        e_t, sc, Woep_l, boe_l, out_e);
        }
        k_nattn<<<NN, 64, 0, stream>>>(offs, csr_src, sc, e_t, Vh, wV, rowV);
        k_nodeB<<<(NN + 63) / 64, 512, 0, stream>>>(wV, rowV, VRp_l, dc_l, logdeg, x_l,
                                                    Wohp_l, boh_l, W1p_l, b1_l, W2p_l, b2_l, out_x);
    }
}